// Round 1
// baseline (837.372 us; speedup 1.0000x reference)
//
#include <hip/hip_runtime.h>

typedef unsigned short u16;
typedef unsigned int u32;
typedef __bf16 bfrag __attribute__((ext_vector_type(8)));
typedef float f32x4 __attribute__((ext_vector_type(4)));

__device__ __forceinline__ u16 f2bf(float f) {
    u32 u = __float_as_uint(f);
    u32 r = (u + 0x7FFFu + ((u >> 16) & 1u)) >> 16;
    return (u16)r;
}
__device__ __forceinline__ float bf2f(u32 h) {
    return __uint_as_float(h << 16);
}

// ---------------- small precompute kernels ----------------

// u1[c] = ee_w @ lin1_w ; C1[c] = ee_b@lin1_w + lin1_b + ne_b  (layer-1 message consts)
// u2[c] = ee_w @ lin2_w ; C2[c] = ee_b@lin2_w + lin2_b         (layer-2 message consts)
__global__ __launch_bounds__(128) void consts_kernel(
    const float* __restrict__ ne_b, const float* __restrict__ ee_w, const float* __restrict__ ee_b,
    const float* __restrict__ lin1_w, const float* __restrict__ lin1_b,
    const float* __restrict__ lin2_w, const float* __restrict__ lin2_b,
    float* __restrict__ u1, float* __restrict__ C1, float* __restrict__ u2, float* __restrict__ C2)
{
    int c = threadIdx.x;
    float s1 = 0.f, t1 = 0.f, s2 = 0.f, t2 = 0.f;
    for (int k = 0; k < 128; ++k) {
        float w1 = lin1_w[k * 128 + c];
        float w2 = lin2_w[k * 128 + c];
        float ew = ee_w[k], eb = ee_b[k];
        s1 = fmaf(ew, w1, s1); t1 = fmaf(eb, w1, t1);
        s2 = fmaf(ew, w2, s2); t2 = fmaf(eb, w2, t2);
    }
    u1[c] = s1; C1[c] = t1 + lin1_b[c] + ne_b[c];
    u2[c] = s2; C2[c] = t2 + lin2_b[c];
}

// Pack W [128x128] fp32 row-major -> MFMA B-fragment order, split into bf16 hi + lo.
// packed[(((ks*8+ct)*64)+lane)*8 + j] = W[ks*32 + (lane>>4)*8 + j][ct*16 + (lane&15)]
__global__ __launch_bounds__(256) void prepack_kernel(
    const float* __restrict__ w, u16* __restrict__ hi, u16* __restrict__ lo)
{
    int o = blockIdx.x * 256 + threadIdx.x;   // 0..16383
    int j = o & 7;
    int lane = (o >> 3) & 63;
    int ct = (o >> 9) & 7;
    int ks = o >> 12;
    int k = ks * 32 + ((lane >> 4) * 8) + j;
    int c = ct * 16 + (lane & 15);
    float v = w[k * 128 + c];
    u16 h = f2bf(v);
    float vh = bf2f(h);
    u16 l = f2bf(v - vh);
    hi[o] = h; lo[o] = l;
}

// ---------------- CSR build ----------------

__global__ __launch_bounds__(256) void count_kernel(
    const int* __restrict__ dst, int* __restrict__ deg, int E)
{
    int e = blockIdx.x * 256 + threadIdx.x;
    if (e < E) atomicAdd(&deg[dst[e]], 1);
}

__global__ __launch_bounds__(1024) void scan1_kernel(
    const int* __restrict__ deg, int* __restrict__ incl, int* __restrict__ bsum, int n)
{
    __shared__ int buf[1024];
    int i = blockIdx.x * 1024 + threadIdx.x;
    int v = (i < n) ? deg[i] : 0;
    buf[threadIdx.x] = v;
    __syncthreads();
    for (int off = 1; off < 1024; off <<= 1) {
        int t = (threadIdx.x >= off) ? buf[threadIdx.x - off] : 0;
        __syncthreads();
        buf[threadIdx.x] += t;
        __syncthreads();
    }
    if (i < n) incl[i] = buf[threadIdx.x];
    if (threadIdx.x == 1023) bsum[blockIdx.x] = buf[1023];
}

__global__ __launch_bounds__(64) void scan2_kernel(
    const int* __restrict__ bsum, int* __restrict__ boff, int nb)
{
    if (threadIdx.x == 0 && blockIdx.x == 0) {
        int run = 0;
        for (int b = 0; b < nb; ++b) { boff[b] = run; run += bsum[b]; }
    }
}

__global__ __launch_bounds__(1024) void scan3_kernel(
    const int* __restrict__ deg, const int* __restrict__ incl, const int* __restrict__ boff,
    int* __restrict__ rowptr, int* __restrict__ cursor, int n)
{
    int i = blockIdx.x * 1024 + threadIdx.x;
    if (i < n) {
        int inc = boff[blockIdx.x] + incl[i];
        int ex = inc - deg[i];
        rowptr[i] = ex;
        cursor[i] = ex;
        if (i == n - 1) rowptr[n] = inc;
    }
}

__global__ __launch_bounds__(256) void scatter_kernel(
    const int* __restrict__ src, const int* __restrict__ dst, const float* __restrict__ eattr,
    int* __restrict__ cursor, int* __restrict__ srcs, float* __restrict__ attrs, int E)
{
    int e = blockIdx.x * 256 + threadIdx.x;
    if (e < E) {
        int d = dst[e];
        int p = atomicAdd(&cursor[d], 1);
        srcs[p] = src[e];
        attrs[p] = eattr[e];
    }
}

// ---------------- pull aggregation ----------------

// Layer 1: agg[n][c] = sum_e relu(x[src]*ne_w[c] + a*u1[c] + C1[c]); z1 = x[n]*ne_w+ne_b + agg
__global__ __launch_bounds__(256) void pull1_kernel(
    const float* __restrict__ x,
    const int* __restrict__ rowptr, const int* __restrict__ srcs, const float* __restrict__ attrs,
    const float* __restrict__ ne_w, const float* __restrict__ ne_b,
    const float* __restrict__ u1, const float* __restrict__ C1,
    u16* __restrict__ zb, int N)
{
    int lane = threadIdx.x & 63;
    int node = blockIdx.x * 4 + (threadIdx.x >> 6);
    if (node >= N) return;
    float2 A  = *(const float2*)(ne_w + 2 * lane);
    float2 Bv = *(const float2*)(u1   + 2 * lane);
    float2 Cv = *(const float2*)(C1   + 2 * lane);
    float2 nb = *(const float2*)(ne_b + 2 * lane);
    int jb = rowptr[node], je = rowptr[node + 1];
    float a0 = 0.f, a1 = 0.f;
    for (int j = jb; j < je; ++j) {
        int s = srcs[j];
        float av = attrs[j];
        float xs = x[s];
        float m0 = fmaf(xs, A.x, fmaf(av, Bv.x, Cv.x));
        float m1 = fmaf(xs, A.y, fmaf(av, Bv.y, Cv.y));
        a0 += fmaxf(m0, 0.f);
        a1 += fmaxf(m1, 0.f);
    }
    float xn = x[node];
    float z0 = fmaf(xn, A.x, nb.x) + a0;
    float z1 = fmaf(xn, A.y, nb.y) + a1;
    ((u32*)(zb + (long)node * 128))[lane] = (u32)f2bf(z0) | ((u32)f2bf(z1) << 16);
}

// Layer 2: agg[n][c] = sum_e relu(h1[src][c] + a*u2[c] + C2[c]); z2 = h1[n] + agg
__global__ __launch_bounds__(256) void pull2_kernel(
    const u16* __restrict__ h1b,
    const int* __restrict__ rowptr, const int* __restrict__ srcs, const float* __restrict__ attrs,
    const float* __restrict__ u2, const float* __restrict__ C2,
    u16* __restrict__ zb2, int N)
{
    int lane = threadIdx.x & 63;
    int node = blockIdx.x * 4 + (threadIdx.x >> 6);
    if (node >= N) return;
    float2 Bv = *(const float2*)(u2 + 2 * lane);
    float2 Cv = *(const float2*)(C2 + 2 * lane);
    int jb = rowptr[node], je = rowptr[node + 1];
    float a0 = 0.f, a1 = 0.f;
    for (int j = jb; j < je; ++j) {
        int s = srcs[j];
        float av = attrs[j];
        u32 hv = ((const u32*)(h1b + (long)s * 128))[lane];
        float h0 = bf2f(hv & 0xFFFFu);
        float h1 = bf2f(hv >> 16);
        float m0 = h0 + fmaf(av, Bv.x, Cv.x);
        float m1 = h1 + fmaf(av, Bv.y, Cv.y);
        a0 += fmaxf(m0, 0.f);
        a1 += fmaxf(m1, 0.f);
    }
    u32 hn = ((const u32*)(h1b + (long)node * 128))[lane];
    float z0 = bf2f(hn & 0xFFFFu) + a0;
    float z1 = bf2f(hn >> 16) + a1;
    ((u32*)(zb2 + (long)node * 128))[lane] = (u32)f2bf(z0) | ((u32)f2bf(z1) << 16);
}

// ---------------- fused 2-GEMM node MLP (bf16 MFMA, split weights) ----------------
// out = relu( relu(z @ W1 + b1) @ W2 + b2 ), z bf16 [Npad,128], weights prepacked hi/lo.
__global__ __launch_bounds__(256) void mlp_kernel(
    const u16* __restrict__ zb,
    const u16* __restrict__ w1hi, const u16* __restrict__ w1lo,
    const u16* __restrict__ w2hi, const u16* __restrict__ w2lo,
    const float* __restrict__ b1, const float* __restrict__ b2,
    u16* __restrict__ outb)
{
    __shared__ __align__(16) u16 tls[64][136];
    const int lane = threadIdx.x & 63;
    const int wv = threadIdx.x >> 6;
    const int m = lane & 15;
    const int q = lane >> 4;
    const int ko = q * 8;
    const long tile_row = (long)blockIdx.x * 64 + wv * 16;

    f32x4 acc[8];
#pragma unroll
    for (int ct = 0; ct < 8; ++ct) acc[ct] = (f32x4){0.f, 0.f, 0.f, 0.f};

#pragma unroll
    for (int ks = 0; ks < 4; ++ks) {
        bfrag a = *(const bfrag*)(zb + (tile_row + m) * 128 + ks * 32 + ko);
#pragma unroll
        for (int ct = 0; ct < 8; ++ct) {
            const int off = (((ks * 8 + ct) * 64) + lane) * 8;
            bfrag bh = *(const bfrag*)(w1hi + off);
            bfrag bl = *(const bfrag*)(w1lo + off);
            acc[ct] = __builtin_amdgcn_mfma_f32_16x16x32_bf16(a, bh, acc[ct], 0, 0, 0);
            acc[ct] = __builtin_amdgcn_mfma_f32_16x16x32_bf16(a, bl, acc[ct], 0, 0, 0);
        }
    }
    // epilogue 1: bias + relu -> LDS (t in row-major for A-frag reads)
#pragma unroll
    for (int ct = 0; ct < 8; ++ct) {
        float bv = b1[ct * 16 + m];
#pragma unroll
        for (int r = 0; r < 4; ++r) {
            float v = fmaxf(acc[ct][r] + bv, 0.f);
            tls[wv * 16 + q * 4 + r][ct * 16 + m] = f2bf(v);
        }
    }
    __syncthreads();

    f32x4 acc2[8];
#pragma unroll
    for (int ct = 0; ct < 8; ++ct) acc2[ct] = (f32x4){0.f, 0.f, 0.f, 0.f};

#pragma unroll
    for (int ks = 0; ks < 4; ++ks) {
        bfrag a = *(const bfrag*)(&tls[wv * 16 + m][ks * 32 + ko]);
#pragma unroll
        for (int ct = 0; ct < 8; ++ct) {
            const int off = (((ks * 8 + ct) * 64) + lane) * 8;
            bfrag bh = *(const bfrag*)(w2hi + off);
            bfrag bl = *(const bfrag*)(w2lo + off);
            acc2[ct] = __builtin_amdgcn_mfma_f32_16x16x32_bf16(a, bh, acc2[ct], 0, 0, 0);
            acc2[ct] = __builtin_amdgcn_mfma_f32_16x16x32_bf16(a, bl, acc2[ct], 0, 0, 0);
        }
    }
    // epilogue 2: bias + relu -> LDS (reuse), then coalesced copy out
#pragma unroll
    for (int ct = 0; ct < 8; ++ct) {
        float bv = b2[ct * 16 + m];
#pragma unroll
        for (int r = 0; r < 4; ++r) {
            float v = fmaxf(acc2[ct][r] + bv, 0.f);
            tls[wv * 16 + q * 4 + r][ct * 16 + m] = f2bf(v);
        }
    }
    __syncthreads();
    const long base_row = (long)blockIdx.x * 64;
#pragma unroll
    for (int it = 0; it < 4; ++it) {
        int chunk = threadIdx.x + it * 256;   // 0..1023
        int row = chunk >> 4;
        int c8 = (chunk & 15) * 8;
        *(uint4*)(outb + (base_row + row) * 128 + c8) = *(const uint4*)(&tls[row][c8]);
    }
}

// ---------------- global mean pool ----------------
__global__ __launch_bounds__(256) void pool_kernel(
    const u16* __restrict__ h2b, const int* __restrict__ batch, float* __restrict__ out, int n)
{
    int g = blockIdx.x;
    int c = threadIdx.x & 127;
    int half = threadIdx.x >> 7;
    // lower_bound for g and g+1 in sorted batch
    int lo = 0, hi = n;
    while (lo < hi) { int mid = (lo + hi) >> 1; if (batch[mid] < g) lo = mid + 1; else hi = mid; }
    int s = lo;
    lo = s; hi = n;
    while (lo < hi) { int mid = (lo + hi) >> 1; if (batch[mid] < g + 1) lo = mid + 1; else hi = mid; }
    int e = lo;
    float sum = 0.f;
    for (int r = s + half; r < e; r += 2) sum += bf2f((u32)h2b[(long)r * 128 + c]);
    __shared__ float red[256];
    red[threadIdx.x] = sum;
    __syncthreads();
    if (half == 0) {
        int cnt = e - s;
        float tot = sum + red[threadIdx.x + 128];
        out[g * 128 + c] = tot / (float)(cnt > 0 ? cnt : 1);
    }
}

// ---------------- launch ----------------
extern "C" void kernel_launch(void* const* d_in, const int* in_sizes, int n_in,
                              void* d_out, int out_size, void* d_ws, size_t ws_size,
                              hipStream_t stream)
{
    const float* x      = (const float*)d_in[0];
    const int*   ei     = (const int*)d_in[1];
    const float* eattr  = (const float*)d_in[2];
    const int*   batch  = (const int*)d_in[3];
    const float* ne_w   = (const float*)d_in[4];
    const float* ne_b   = (const float*)d_in[5];
    const float* ee_w   = (const float*)d_in[6];
    const float* ee_b   = (const float*)d_in[7];
    const float* lin1_w = (const float*)d_in[8];
    const float* lin1_b = (const float*)d_in[9];
    const float* w11    = (const float*)d_in[10];
    const float* b11    = (const float*)d_in[11];
    const float* w12    = (const float*)d_in[12];
    const float* b12    = (const float*)d_in[13];
    const float* lin2_w = (const float*)d_in[14];
    const float* lin2_b = (const float*)d_in[15];
    const float* w21    = (const float*)d_in[16];
    const float* b21    = (const float*)d_in[17];
    const float* w22    = (const float*)d_in[18];
    const float* b22    = (const float*)d_in[19];

    const int N = in_sizes[0];
    const int E = in_sizes[2];
    const int G = out_size / 128;
    const int Npad = ((N + 63) / 64) * 64;
    const int* esrc = ei;
    const int* edst = ei + E;

    char* p = (char*)d_ws;
    auto alloc = [&](size_t bytes) -> void* {
        void* r = (void*)p;
        p += (bytes + 255) & ~(size_t)255;
        return r;
    };
    float* u1 = (float*)alloc(128 * 4);
    float* C1 = (float*)alloc(128 * 4);
    float* u2 = (float*)alloc(128 * 4);
    float* C2 = (float*)alloc(128 * 4);
    int* deg    = (int*)alloc((size_t)N * 4);
    int* incl   = (int*)alloc((size_t)N * 4);
    int* bsum   = (int*)alloc(1024);
    int* boff   = (int*)alloc(1024);
    int* rowptr = (int*)alloc(((size_t)N + 1) * 4);
    int* cursor = (int*)alloc((size_t)N * 4);
    int* srcs   = (int*)alloc((size_t)E * 4);
    float* attrs = (float*)alloc((size_t)E * 4);
    u16* w11hi = (u16*)alloc(16384 * 2);
    u16* w11lo = (u16*)alloc(16384 * 2);
    u16* w12hi = (u16*)alloc(16384 * 2);
    u16* w12lo = (u16*)alloc(16384 * 2);
    u16* w21hi = (u16*)alloc(16384 * 2);
    u16* w21lo = (u16*)alloc(16384 * 2);
    u16* w22hi = (u16*)alloc(16384 * 2);
    u16* w22lo = (u16*)alloc(16384 * 2);
    u16* bufA = (u16*)alloc((size_t)Npad * 128 * 2);
    u16* bufB = (u16*)alloc((size_t)Npad * 128 * 2);

    const int nbScan = (N + 1023) / 1024;

    hipMemsetAsync(deg, 0, (size_t)N * 4, stream);
    consts_kernel<<<1, 128, 0, stream>>>(ne_b, ee_w, ee_b, lin1_w, lin1_b, lin2_w, lin2_b,
                                         u1, C1, u2, C2);
    prepack_kernel<<<64, 256, 0, stream>>>(w11, w11hi, w11lo);
    prepack_kernel<<<64, 256, 0, stream>>>(w12, w12hi, w12lo);
    prepack_kernel<<<64, 256, 0, stream>>>(w21, w21hi, w21lo);
    prepack_kernel<<<64, 256, 0, stream>>>(w22, w22hi, w22lo);

    count_kernel<<<(E + 255) / 256, 256, 0, stream>>>(edst, deg, E);
    scan1_kernel<<<nbScan, 1024, 0, stream>>>(deg, incl, bsum, N);
    scan2_kernel<<<1, 64, 0, stream>>>(bsum, boff, nbScan);
    scan3_kernel<<<nbScan, 1024, 0, stream>>>(deg, incl, boff, rowptr, cursor, N);
    scatter_kernel<<<(E + 255) / 256, 256, 0, stream>>>(esrc, edst, eattr, cursor, srcs, attrs, E);

    pull1_kernel<<<(N + 3) / 4, 256, 0, stream>>>(x, rowptr, srcs, attrs, ne_w, ne_b, u1, C1,
                                                  bufA, N);
    mlp_kernel<<<Npad / 64, 256, 0, stream>>>(bufA, w11hi, w11lo, w12hi, w12lo, b11, b12, bufB);
    pull2_kernel<<<(N + 3) / 4, 256, 0, stream>>>(bufB, rowptr, srcs, attrs, u2, C2, bufA, N);
    mlp_kernel<<<Npad / 64, 256, 0, stream>>>(bufA, w21hi, w21lo, w22hi, w22lo, b21, b22, bufB);

    pool_kernel<<<G, 256, 0, stream>>>(bufB, batch, (float*)d_out, N);
}

// Round 2
// 676.192 us; speedup vs baseline: 1.2384x; 1.2384x over previous
//
#include <hip/hip_runtime.h>

typedef unsigned short u16;
typedef unsigned int u32;
typedef __bf16 bfrag __attribute__((ext_vector_type(8)));
typedef float f32x4 __attribute__((ext_vector_type(4)));

__device__ __forceinline__ u16 f2bf(float f) {
    u32 u = __float_as_uint(f);
    u32 r = (u + 0x7FFFu + ((u >> 16) & 1u)) >> 16;
    return (u16)r;
}
__device__ __forceinline__ float bf2f(u32 h) {
    return __uint_as_float(h << 16);
}

// ---------------- small precompute kernels ----------------

__global__ __launch_bounds__(128) void consts_kernel(
    const float* __restrict__ ne_b, const float* __restrict__ ee_w, const float* __restrict__ ee_b,
    const float* __restrict__ lin1_w, const float* __restrict__ lin1_b,
    const float* __restrict__ lin2_w, const float* __restrict__ lin2_b,
    float* __restrict__ u1, float* __restrict__ C1, float* __restrict__ u2, float* __restrict__ C2)
{
    int c = threadIdx.x;
    float s1 = 0.f, t1 = 0.f, s2 = 0.f, t2 = 0.f;
    for (int k = 0; k < 128; ++k) {
        float w1 = lin1_w[k * 128 + c];
        float w2 = lin2_w[k * 128 + c];
        float ew = ee_w[k], eb = ee_b[k];
        s1 = fmaf(ew, w1, s1); t1 = fmaf(eb, w1, t1);
        s2 = fmaf(ew, w2, s2); t2 = fmaf(eb, w2, t2);
    }
    u1[c] = s1; C1[c] = t1 + lin1_b[c] + ne_b[c];
    u2[c] = s2; C2[c] = t2 + lin2_b[c];
}

// Pack W [128x128] fp32 row-major -> MFMA B-fragment order, split into bf16 hi + lo.
__global__ __launch_bounds__(256) void prepack_kernel(
    const float* __restrict__ w, u16* __restrict__ hi, u16* __restrict__ lo)
{
    int o = blockIdx.x * 256 + threadIdx.x;   // 0..16383
    int j = o & 7;
    int lane = (o >> 3) & 63;
    int ct = (o >> 9) & 7;
    int ks = o >> 12;
    int k = ks * 32 + ((lane >> 4) * 8) + j;
    int c = ct * 16 + (lane & 15);
    float v = w[k * 128 + c];
    u16 h = f2bf(v);
    float vh = bf2f(h);
    u16 l = f2bf(v - vh);
    hi[o] = h; lo[o] = l;
}

// ---------------- CSR build ----------------

__global__ __launch_bounds__(256) void count_kernel(
    const int* __restrict__ dst, int* __restrict__ deg, int E)
{
    int e = blockIdx.x * 256 + threadIdx.x;
    if (e < E) atomicAdd(&deg[dst[e]], 1);
}

__global__ __launch_bounds__(1024) void scan1_kernel(
    const int* __restrict__ deg, int* __restrict__ incl, int* __restrict__ bsum, int n)
{
    __shared__ int buf[1024];
    int i = blockIdx.x * 1024 + threadIdx.x;
    int v = (i < n) ? deg[i] : 0;
    buf[threadIdx.x] = v;
    __syncthreads();
    for (int off = 1; off < 1024; off <<= 1) {
        int t = (threadIdx.x >= off) ? buf[threadIdx.x - off] : 0;
        __syncthreads();
        buf[threadIdx.x] += t;
        __syncthreads();
    }
    if (i < n) incl[i] = buf[threadIdx.x];
    if (threadIdx.x == 1023) bsum[blockIdx.x] = buf[1023];
}

// parallel single-block exclusive scan of block sums (nb <= 1024)
__global__ __launch_bounds__(1024) void scan2_kernel(
    const int* __restrict__ bsum, int* __restrict__ boff, int nb)
{
    __shared__ int buf[1024];
    int i = threadIdx.x;
    int v = (i < nb) ? bsum[i] : 0;
    buf[i] = v;
    __syncthreads();
    for (int off = 1; off < 1024; off <<= 1) {
        int t = (i >= off) ? buf[i - off] : 0;
        __syncthreads();
        buf[i] += t;
        __syncthreads();
    }
    if (i < nb) boff[i] = buf[i] - v;
}

__global__ __launch_bounds__(1024) void scan3_kernel(
    const int* __restrict__ deg, const int* __restrict__ incl, const int* __restrict__ boff,
    int* __restrict__ rowptr, int* __restrict__ cursor, int n)
{
    int i = blockIdx.x * 1024 + threadIdx.x;
    if (i < n) {
        int inc = boff[blockIdx.x] + incl[i];
        int ex = inc - deg[i];
        rowptr[i] = ex;
        cursor[i] = ex;
        if (i == n - 1) rowptr[n] = inc;
    }
}

__global__ __launch_bounds__(256) void scatter_kernel(
    const int* __restrict__ src, const int* __restrict__ dst, const float* __restrict__ eattr,
    int* __restrict__ cursor, int* __restrict__ srcs, float* __restrict__ attrs, int E)
{
    int e = blockIdx.x * 256 + threadIdx.x;
    if (e < E) {
        int d = dst[e];
        int p = atomicAdd(&cursor[d], 1);
        srcs[p] = src[e];
        attrs[p] = eattr[e];
    }
}

// ---------------- pull aggregation ----------------

__global__ __launch_bounds__(256) void pull1_kernel(
    const float* __restrict__ x,
    const int* __restrict__ rowptr, const int* __restrict__ srcs, const float* __restrict__ attrs,
    const float* __restrict__ ne_w, const float* __restrict__ ne_b,
    const float* __restrict__ u1, const float* __restrict__ C1,
    u16* __restrict__ zb, int N)
{
    int lane = threadIdx.x & 63;
    int node = blockIdx.x * 4 + (threadIdx.x >> 6);
    if (node >= N) return;
    float2 A  = *(const float2*)(ne_w + 2 * lane);
    float2 Bv = *(const float2*)(u1   + 2 * lane);
    float2 Cv = *(const float2*)(C1   + 2 * lane);
    float2 nb = *(const float2*)(ne_b + 2 * lane);
    int jb = rowptr[node], je = rowptr[node + 1];
    float a0 = 0.f, a1 = 0.f;
    for (int j = jb; j < je; ++j) {
        int s = srcs[j];
        float av = attrs[j];
        float xs = x[s];
        float m0 = fmaf(xs, A.x, fmaf(av, Bv.x, Cv.x));
        float m1 = fmaf(xs, A.y, fmaf(av, Bv.y, Cv.y));
        a0 += fmaxf(m0, 0.f);
        a1 += fmaxf(m1, 0.f);
    }
    float xn = x[node];
    float z0 = fmaf(xn, A.x, nb.x) + a0;
    float z1 = fmaf(xn, A.y, nb.y) + a1;
    ((u32*)(zb + (long)node * 128))[lane] = (u32)f2bf(z0) | ((u32)f2bf(z1) << 16);
}

__global__ __launch_bounds__(256) void pull2_kernel(
    const u16* __restrict__ h1b,
    const int* __restrict__ rowptr, const int* __restrict__ srcs, const float* __restrict__ attrs,
    const float* __restrict__ u2, const float* __restrict__ C2,
    u16* __restrict__ zb2, int N)
{
    int lane = threadIdx.x & 63;
    int node = blockIdx.x * 4 + (threadIdx.x >> 6);
    if (node >= N) return;
    float2 Bv = *(const float2*)(u2 + 2 * lane);
    float2 Cv = *(const float2*)(C2 + 2 * lane);
    int jb = rowptr[node], je = rowptr[node + 1];
    float a0 = 0.f, a1 = 0.f;
    for (int j = jb; j < je; ++j) {
        int s = srcs[j];
        float av = attrs[j];
        u32 hv = ((const u32*)(h1b + (long)s * 128))[lane];
        float h0 = bf2f(hv & 0xFFFFu);
        float h1 = bf2f(hv >> 16);
        float m0 = h0 + fmaf(av, Bv.x, Cv.x);
        float m1 = h1 + fmaf(av, Bv.y, Cv.y);
        a0 += fmaxf(m0, 0.f);
        a1 += fmaxf(m1, 0.f);
    }
    u32 hn = ((const u32*)(h1b + (long)node * 128))[lane];
    float z0 = bf2f(hn & 0xFFFFu) + a0;
    float z1 = bf2f(hn >> 16) + a1;
    ((u32*)(zb2 + (long)node * 128))[lane] = (u32)f2bf(z0) | ((u32)f2bf(z1) << 16);
}

// ---------------- fused 2-GEMM node MLP (bf16 MFMA, split weights) ----------------
__global__ __launch_bounds__(256) void mlp_kernel(
    const u16* __restrict__ zb,
    const u16* __restrict__ w1hi, const u16* __restrict__ w1lo,
    const u16* __restrict__ w2hi, const u16* __restrict__ w2lo,
    const float* __restrict__ b1, const float* __restrict__ b2,
    u16* __restrict__ outb)
{
    __shared__ __align__(16) u16 tls[64][136];
    const int lane = threadIdx.x & 63;
    const int wv = threadIdx.x >> 6;
    const int m = lane & 15;
    const int q = lane >> 4;
    const int ko = q * 8;
    const long tile_row = (long)blockIdx.x * 64 + wv * 16;

    f32x4 acc[8];
#pragma unroll
    for (int ct = 0; ct < 8; ++ct) acc[ct] = (f32x4){0.f, 0.f, 0.f, 0.f};

#pragma unroll
    for (int ks = 0; ks < 4; ++ks) {
        bfrag a = *(const bfrag*)(zb + (tile_row + m) * 128 + ks * 32 + ko);
#pragma unroll
        for (int ct = 0; ct < 8; ++ct) {
            const int off = (((ks * 8 + ct) * 64) + lane) * 8;
            bfrag bh = *(const bfrag*)(w1hi + off);
            bfrag bl = *(const bfrag*)(w1lo + off);
            acc[ct] = __builtin_amdgcn_mfma_f32_16x16x32_bf16(a, bh, acc[ct], 0, 0, 0);
            acc[ct] = __builtin_amdgcn_mfma_f32_16x16x32_bf16(a, bl, acc[ct], 0, 0, 0);
        }
    }
#pragma unroll
    for (int ct = 0; ct < 8; ++ct) {
        float bv = b1[ct * 16 + m];
#pragma unroll
        for (int r = 0; r < 4; ++r) {
            float v = fmaxf(acc[ct][r] + bv, 0.f);
            tls[wv * 16 + q * 4 + r][ct * 16 + m] = f2bf(v);
        }
    }
    __syncthreads();

    f32x4 acc2[8];
#pragma unroll
    for (int ct = 0; ct < 8; ++ct) acc2[ct] = (f32x4){0.f, 0.f, 0.f, 0.f};

#pragma unroll
    for (int ks = 0; ks < 4; ++ks) {
        bfrag a = *(const bfrag*)(&tls[wv * 16 + m][ks * 32 + ko]);
#pragma unroll
        for (int ct = 0; ct < 8; ++ct) {
            const int off = (((ks * 8 + ct) * 64) + lane) * 8;
            bfrag bh = *(const bfrag*)(w2hi + off);
            bfrag bl = *(const bfrag*)(w2lo + off);
            acc2[ct] = __builtin_amdgcn_mfma_f32_16x16x32_bf16(a, bh, acc2[ct], 0, 0, 0);
            acc2[ct] = __builtin_amdgcn_mfma_f32_16x16x32_bf16(a, bl, acc2[ct], 0, 0, 0);
        }
    }
#pragma unroll
    for (int ct = 0; ct < 8; ++ct) {
        float bv = b2[ct * 16 + m];
#pragma unroll
        for (int r = 0; r < 4; ++r) {
            float v = fmaxf(acc2[ct][r] + bv, 0.f);
            tls[wv * 16 + q * 4 + r][ct * 16 + m] = f2bf(v);
        }
    }
    __syncthreads();
    const long base_row = (long)blockIdx.x * 64;
#pragma unroll
    for (int it = 0; it < 4; ++it) {
        int chunk = threadIdx.x + it * 256;   // 0..1023
        int row = chunk >> 4;
        int c8 = (chunk & 15) * 8;
        *(uint4*)(outb + (base_row + row) * 128 + c8) = *(const uint4*)(&tls[row][c8]);
    }
}

// ---------------- global mean pool (two-stage, grid-parallel) ----------------

// stage 1: each block reduces a contiguous row chunk; register-accumulate per
// graph run (batch is sorted), flush one atomic per boundary crossing.
__global__ __launch_bounds__(128) void pool1_kernel(
    const u16* __restrict__ h2b, const int* __restrict__ batch,
    float* __restrict__ acc, int N, int rows_per_block)
{
    int c = threadIdx.x;
    int r0 = blockIdx.x * rows_per_block;
    if (r0 >= N) return;
    int r1 = r0 + rows_per_block;
    if (r1 > N) r1 = N;
    int cur = batch[r0];
    float sum = 0.f;
    for (int r = r0; r < r1; ++r) {
        int g = batch[r];
        float v = bf2f((u32)h2b[(long)r * 128 + c]);
        if (g != cur) {
            atomicAdd(&acc[cur * 128 + c], sum);
            sum = 0.f;
            cur = g;
        }
        sum += v;
    }
    atomicAdd(&acc[cur * 128 + c], sum);
}

// stage 2: divide by per-graph counts (binary search in sorted batch)
__global__ __launch_bounds__(128) void pool2_kernel(
    const float* __restrict__ acc, const int* __restrict__ batch,
    float* __restrict__ out, int n)
{
    int g = blockIdx.x;
    int c = threadIdx.x;
    int lo = 0, hi = n;
    while (lo < hi) { int mid = (lo + hi) >> 1; if (batch[mid] < g) lo = mid + 1; else hi = mid; }
    int s = lo;
    lo = s; hi = n;
    while (lo < hi) { int mid = (lo + hi) >> 1; if (batch[mid] < g + 1) lo = mid + 1; else hi = mid; }
    int cnt = lo - s;
    out[g * 128 + c] = acc[g * 128 + c] / (float)(cnt > 0 ? cnt : 1);
}

// ---------------- launch ----------------
extern "C" void kernel_launch(void* const* d_in, const int* in_sizes, int n_in,
                              void* d_out, int out_size, void* d_ws, size_t ws_size,
                              hipStream_t stream)
{
    const float* x      = (const float*)d_in[0];
    const int*   ei     = (const int*)d_in[1];
    const float* eattr  = (const float*)d_in[2];
    const int*   batch  = (const int*)d_in[3];
    const float* ne_w   = (const float*)d_in[4];
    const float* ne_b   = (const float*)d_in[5];
    const float* ee_w   = (const float*)d_in[6];
    const float* ee_b   = (const float*)d_in[7];
    const float* lin1_w = (const float*)d_in[8];
    const float* lin1_b = (const float*)d_in[9];
    const float* w11    = (const float*)d_in[10];
    const float* b11    = (const float*)d_in[11];
    const float* w12    = (const float*)d_in[12];
    const float* b12    = (const float*)d_in[13];
    const float* lin2_w = (const float*)d_in[14];
    const float* lin2_b = (const float*)d_in[15];
    const float* w21    = (const float*)d_in[16];
    const float* b21    = (const float*)d_in[17];
    const float* w22    = (const float*)d_in[18];
    const float* b22    = (const float*)d_in[19];

    const int N = in_sizes[0];
    const int E = in_sizes[2];
    const int G = out_size / 128;
    const int Npad = ((N + 63) / 64) * 64;
    const int* esrc = ei;
    const int* edst = ei + E;

    char* p = (char*)d_ws;
    auto alloc = [&](size_t bytes) -> void* {
        void* r = (void*)p;
        p += (bytes + 255) & ~(size_t)255;
        return r;
    };
    float* u1 = (float*)alloc(128 * 4);
    float* C1 = (float*)alloc(128 * 4);
    float* u2 = (float*)alloc(128 * 4);
    float* C2 = (float*)alloc(128 * 4);
    int* deg    = (int*)alloc((size_t)N * 4);
    int* incl   = (int*)alloc((size_t)N * 4);
    int* bsum   = (int*)alloc(4096);
    int* boff   = (int*)alloc(4096);
    int* rowptr = (int*)alloc(((size_t)N + 1) * 4);
    int* cursor = (int*)alloc((size_t)N * 4);
    int* srcs   = (int*)alloc((size_t)E * 4);
    float* attrs = (float*)alloc((size_t)E * 4);
    u16* w11hi = (u16*)alloc(16384 * 2);
    u16* w11lo = (u16*)alloc(16384 * 2);
    u16* w12hi = (u16*)alloc(16384 * 2);
    u16* w12lo = (u16*)alloc(16384 * 2);
    u16* w21hi = (u16*)alloc(16384 * 2);
    u16* w21lo = (u16*)alloc(16384 * 2);
    u16* w22hi = (u16*)alloc(16384 * 2);
    u16* w22lo = (u16*)alloc(16384 * 2);
    u16* bufA = (u16*)alloc((size_t)Npad * 128 * 2);
    u16* bufB = (u16*)alloc((size_t)Npad * 128 * 2);
    float* poolacc = (float*)alloc((size_t)G * 128 * 4);

    const int nbScan = (N + 1023) / 1024;

    hipMemsetAsync(deg, 0, (size_t)N * 4, stream);
    hipMemsetAsync(poolacc, 0, (size_t)G * 128 * 4, stream);
    consts_kernel<<<1, 128, 0, stream>>>(ne_b, ee_w, ee_b, lin1_w, lin1_b, lin2_w, lin2_b,
                                         u1, C1, u2, C2);
    prepack_kernel<<<64, 256, 0, stream>>>(w11, w11hi, w11lo);
    prepack_kernel<<<64, 256, 0, stream>>>(w12, w12hi, w12lo);
    prepack_kernel<<<64, 256, 0, stream>>>(w21, w21hi, w21lo);
    prepack_kernel<<<64, 256, 0, stream>>>(w22, w22hi, w22lo);

    count_kernel<<<(E + 255) / 256, 256, 0, stream>>>(edst, deg, E);
    scan1_kernel<<<nbScan, 1024, 0, stream>>>(deg, incl, bsum, N);
    scan2_kernel<<<1, 1024, 0, stream>>>(bsum, boff, nbScan);
    scan3_kernel<<<nbScan, 1024, 0, stream>>>(deg, incl, boff, rowptr, cursor, N);
    scatter_kernel<<<(E + 255) / 256, 256, 0, stream>>>(esrc, edst, eattr, cursor, srcs, attrs, E);

    pull1_kernel<<<(N + 3) / 4, 256, 0, stream>>>(x, rowptr, srcs, attrs, ne_w, ne_b, u1, C1,
                                                  bufA, N);
    mlp_kernel<<<Npad / 64, 256, 0, stream>>>(bufA, w11hi, w11lo, w12hi, w12lo, b11, b12, bufB);
    pull2_kernel<<<(N + 3) / 4, 256, 0, stream>>>(bufB, rowptr, srcs, attrs, u2, C2, bufA, N);
    mlp_kernel<<<Npad / 64, 256, 0, stream>>>(bufA, w21hi, w21lo, w22hi, w22lo, b21, b22, bufB);

    const int rows_per_block = 128;
    pool1_kernel<<<(N + rows_per_block - 1) / rows_per_block, 128, 0, stream>>>(
        bufB, batch, poolacc, N, rows_per_block);
    pool2_kernel<<<G, 128, 0, stream>>>(poolacc, batch, (float*)d_out, N);
}

// Round 3
// 564.077 us; speedup vs baseline: 1.4845x; 1.1988x over previous
//
#include <hip/hip_runtime.h>

typedef unsigned short u16;
typedef unsigned int u32;
typedef __bf16 bfrag __attribute__((ext_vector_type(8)));
typedef float f32x4 __attribute__((ext_vector_type(4)));

__device__ __forceinline__ u16 f2bf(float f) {
    u32 u = __float_as_uint(f);
    u32 r = (u + 0x7FFFu + ((u >> 16) & 1u)) >> 16;
    return (u16)r;
}
__device__ __forceinline__ float bf2f(u32 h) {
    return __uint_as_float(h << 16);
}

// ---------------- small precompute kernels ----------------

__global__ __launch_bounds__(128) void consts_kernel(
    const float* __restrict__ ne_b, const float* __restrict__ ee_w, const float* __restrict__ ee_b,
    const float* __restrict__ lin1_w, const float* __restrict__ lin1_b,
    const float* __restrict__ lin2_w, const float* __restrict__ lin2_b,
    float* __restrict__ u1, float* __restrict__ C1, float* __restrict__ u2, float* __restrict__ C2)
{
    int c = threadIdx.x;
    float s1 = 0.f, t1 = 0.f, s2 = 0.f, t2 = 0.f;
    for (int k = 0; k < 128; ++k) {
        float w1 = lin1_w[k * 128 + c];
        float w2 = lin2_w[k * 128 + c];
        float ew = ee_w[k], eb = ee_b[k];
        s1 = fmaf(ew, w1, s1); t1 = fmaf(eb, w1, t1);
        s2 = fmaf(ew, w2, s2); t2 = fmaf(eb, w2, t2);
    }
    u1[c] = s1; C1[c] = t1 + lin1_b[c] + ne_b[c];
    u2[c] = s2; C2[c] = t2 + lin2_b[c];
}

// Pack W [128x128] fp32 row-major -> MFMA B-fragment order, split into bf16 hi + lo.
__global__ __launch_bounds__(256) void prepack_kernel(
    const float* __restrict__ w, u16* __restrict__ hi, u16* __restrict__ lo)
{
    int o = blockIdx.x * 256 + threadIdx.x;   // 0..16383
    int j = o & 7;
    int lane = (o >> 3) & 63;
    int ct = (o >> 9) & 7;
    int ks = o >> 12;
    int k = ks * 32 + ((lane >> 4) * 8) + j;
    int c = ct * 16 + (lane & 15);
    float v = w[k * 128 + c];
    u16 h = f2bf(v);
    float vh = bf2f(h);
    u16 l = f2bf(v - vh);
    hi[o] = h; lo[o] = l;
}

// ---------------- CSR build ----------------

__global__ __launch_bounds__(256) void count_kernel(
    const int* __restrict__ dst, int* __restrict__ deg, int E)
{
    int e = blockIdx.x * 256 + threadIdx.x;
    if (e < E) atomicAdd(&deg[dst[e]], 1);
}

__global__ __launch_bounds__(1024) void scan1_kernel(
    const int* __restrict__ deg, int* __restrict__ incl, int* __restrict__ bsum, int n)
{
    __shared__ int buf[1024];
    int i = blockIdx.x * 1024 + threadIdx.x;
    int v = (i < n) ? deg[i] : 0;
    buf[threadIdx.x] = v;
    __syncthreads();
    for (int off = 1; off < 1024; off <<= 1) {
        int t = (threadIdx.x >= off) ? buf[threadIdx.x - off] : 0;
        __syncthreads();
        buf[threadIdx.x] += t;
        __syncthreads();
    }
    if (i < n) incl[i] = buf[threadIdx.x];
    if (threadIdx.x == 1023) bsum[blockIdx.x] = buf[1023];
}

// parallel single-block exclusive scan of block sums (nb <= 1024)
__global__ __launch_bounds__(1024) void scan2_kernel(
    const int* __restrict__ bsum, int* __restrict__ boff, int nb)
{
    __shared__ int buf[1024];
    int i = threadIdx.x;
    int v = (i < nb) ? bsum[i] : 0;
    buf[i] = v;
    __syncthreads();
    for (int off = 1; off < 1024; off <<= 1) {
        int t = (i >= off) ? buf[i - off] : 0;
        __syncthreads();
        buf[i] += t;
        __syncthreads();
    }
    if (i < nb) boff[i] = buf[i] - v;
}

__global__ __launch_bounds__(1024) void scan3_kernel(
    const int* __restrict__ deg, const int* __restrict__ incl, const int* __restrict__ boff,
    int* __restrict__ rowptr, int* __restrict__ cursor, int n)
{
    int i = blockIdx.x * 1024 + threadIdx.x;
    if (i < n) {
        int inc = boff[blockIdx.x] + incl[i];
        int ex = inc - deg[i];
        rowptr[i] = ex;
        cursor[i] = ex;
        if (i == n - 1) rowptr[n] = inc;
    }
}

// write (src, attr-bits) as one int2 per edge
__global__ __launch_bounds__(256) void scatter_kernel(
    const int* __restrict__ src, const int* __restrict__ dst, const float* __restrict__ eattr,
    int* __restrict__ cursor, int2* __restrict__ edges, int E)
{
    int e = blockIdx.x * 256 + threadIdx.x;
    if (e < E) {
        int d = dst[e];
        int p = atomicAdd(&cursor[d], 1);
        edges[p] = make_int2(src[e], __float_as_int(eattr[e]));
    }
}

// ---------------- pull aggregation (8-deep MLP unroll) ----------------

__global__ __launch_bounds__(256) void pull1_kernel(
    const float* __restrict__ x,
    const int* __restrict__ rowptr, const int2* __restrict__ edges,
    const float* __restrict__ ne_w, const float* __restrict__ ne_b,
    const float* __restrict__ u1, const float* __restrict__ C1,
    u16* __restrict__ zb, int N)
{
    int lane = threadIdx.x & 63;
    int node = blockIdx.x * 4 + (threadIdx.x >> 6);
    if (node >= N) return;
    float2 A  = *(const float2*)(ne_w + 2 * lane);
    float2 Bv = *(const float2*)(u1   + 2 * lane);
    float2 Cv = *(const float2*)(C1   + 2 * lane);
    float2 nb = *(const float2*)(ne_b + 2 * lane);
    int jb = rowptr[node], je = rowptr[node + 1];
    float a0 = 0.f, a1 = 0.f;
    int j = jb;
    for (; j + 8 <= je; j += 8) {
        float xs[8], av[8];
#pragma unroll
        for (int t = 0; t < 8; ++t) {
            int2 ep = edges[j + t];
            av[t] = __int_as_float(ep.y);
            xs[t] = x[ep.x];
        }
#pragma unroll
        for (int t = 0; t < 8; ++t) {
            float m0 = fmaf(xs[t], A.x, fmaf(av[t], Bv.x, Cv.x));
            float m1 = fmaf(xs[t], A.y, fmaf(av[t], Bv.y, Cv.y));
            a0 += fmaxf(m0, 0.f);
            a1 += fmaxf(m1, 0.f);
        }
    }
    for (; j < je; ++j) {
        int2 ep = edges[j];
        float av = __int_as_float(ep.y);
        float xs = x[ep.x];
        float m0 = fmaf(xs, A.x, fmaf(av, Bv.x, Cv.x));
        float m1 = fmaf(xs, A.y, fmaf(av, Bv.y, Cv.y));
        a0 += fmaxf(m0, 0.f);
        a1 += fmaxf(m1, 0.f);
    }
    float xn = x[node];
    float z0 = fmaf(xn, A.x, nb.x) + a0;
    float z1 = fmaf(xn, A.y, nb.y) + a1;
    ((u32*)(zb + (long)node * 128))[lane] = (u32)f2bf(z0) | ((u32)f2bf(z1) << 16);
}

__global__ __launch_bounds__(256) void pull2_kernel(
    const u16* __restrict__ h1b,
    const int* __restrict__ rowptr, const int2* __restrict__ edges,
    const float* __restrict__ u2, const float* __restrict__ C2,
    u16* __restrict__ zb2, int N)
{
    int lane = threadIdx.x & 63;
    int node = blockIdx.x * 4 + (threadIdx.x >> 6);
    if (node >= N) return;
    float2 Bv = *(const float2*)(u2 + 2 * lane);
    float2 Cv = *(const float2*)(C2 + 2 * lane);
    int jb = rowptr[node], je = rowptr[node + 1];
    float a0 = 0.f, a1 = 0.f;
    int j = jb;
    for (; j + 8 <= je; j += 8) {
        u32 hv[8];
        float av[8];
#pragma unroll
        for (int t = 0; t < 8; ++t) {
            int2 ep = edges[j + t];
            av[t] = __int_as_float(ep.y);
            hv[t] = ((const u32*)(h1b + (long)ep.x * 128))[lane];
        }
#pragma unroll
        for (int t = 0; t < 8; ++t) {
            float m0 = bf2f(hv[t] & 0xFFFFu) + fmaf(av[t], Bv.x, Cv.x);
            float m1 = bf2f(hv[t] >> 16) + fmaf(av[t], Bv.y, Cv.y);
            a0 += fmaxf(m0, 0.f);
            a1 += fmaxf(m1, 0.f);
        }
    }
    for (; j < je; ++j) {
        int2 ep = edges[j];
        float av = __int_as_float(ep.y);
        u32 hv = ((const u32*)(h1b + (long)ep.x * 128))[lane];
        float m0 = bf2f(hv & 0xFFFFu) + fmaf(av, Bv.x, Cv.x);
        float m1 = bf2f(hv >> 16) + fmaf(av, Bv.y, Cv.y);
        a0 += fmaxf(m0, 0.f);
        a1 += fmaxf(m1, 0.f);
    }
    u32 hn = ((const u32*)(h1b + (long)node * 128))[lane];
    float z0 = bf2f(hn & 0xFFFFu) + a0;
    float z1 = bf2f(hn >> 16) + a1;
    ((u32*)(zb2 + (long)node * 128))[lane] = (u32)f2bf(z0) | ((u32)f2bf(z1) << 16);
}

// ---------------- fused 2-GEMM node MLP (bf16 MFMA, split weights) ----------------
__global__ __launch_bounds__(256) void mlp_kernel(
    const u16* __restrict__ zb,
    const u16* __restrict__ w1hi, const u16* __restrict__ w1lo,
    const u16* __restrict__ w2hi, const u16* __restrict__ w2lo,
    const float* __restrict__ b1, const float* __restrict__ b2,
    u16* __restrict__ outb)
{
    __shared__ __align__(16) u16 tls[64][136];
    const int lane = threadIdx.x & 63;
    const int wv = threadIdx.x >> 6;
    const int m = lane & 15;
    const int q = lane >> 4;
    const int ko = q * 8;
    const long tile_row = (long)blockIdx.x * 64 + wv * 16;

    f32x4 acc[8];
#pragma unroll
    for (int ct = 0; ct < 8; ++ct) acc[ct] = (f32x4){0.f, 0.f, 0.f, 0.f};

#pragma unroll
    for (int ks = 0; ks < 4; ++ks) {
        bfrag a = *(const bfrag*)(zb + (tile_row + m) * 128 + ks * 32 + ko);
#pragma unroll
        for (int ct = 0; ct < 8; ++ct) {
            const int off = (((ks * 8 + ct) * 64) + lane) * 8;
            bfrag bh = *(const bfrag*)(w1hi + off);
            bfrag bl = *(const bfrag*)(w1lo + off);
            acc[ct] = __builtin_amdgcn_mfma_f32_16x16x32_bf16(a, bh, acc[ct], 0, 0, 0);
            acc[ct] = __builtin_amdgcn_mfma_f32_16x16x32_bf16(a, bl, acc[ct], 0, 0, 0);
        }
    }
#pragma unroll
    for (int ct = 0; ct < 8; ++ct) {
        float bv = b1[ct * 16 + m];
#pragma unroll
        for (int r = 0; r < 4; ++r) {
            float v = fmaxf(acc[ct][r] + bv, 0.f);
            tls[wv * 16 + q * 4 + r][ct * 16 + m] = f2bf(v);
        }
    }
    __syncthreads();

    f32x4 acc2[8];
#pragma unroll
    for (int ct = 0; ct < 8; ++ct) acc2[ct] = (f32x4){0.f, 0.f, 0.f, 0.f};

#pragma unroll
    for (int ks = 0; ks < 4; ++ks) {
        bfrag a = *(const bfrag*)(&tls[wv * 16 + m][ks * 32 + ko]);
#pragma unroll
        for (int ct = 0; ct < 8; ++ct) {
            const int off = (((ks * 8 + ct) * 64) + lane) * 8;
            bfrag bh = *(const bfrag*)(w2hi + off);
            bfrag bl = *(const bfrag*)(w2lo + off);
            acc2[ct] = __builtin_amdgcn_mfma_f32_16x16x32_bf16(a, bh, acc2[ct], 0, 0, 0);
            acc2[ct] = __builtin_amdgcn_mfma_f32_16x16x32_bf16(a, bl, acc2[ct], 0, 0, 0);
        }
    }
#pragma unroll
    for (int ct = 0; ct < 8; ++ct) {
        float bv = b2[ct * 16 + m];
#pragma unroll
        for (int r = 0; r < 4; ++r) {
            float v = fmaxf(acc2[ct][r] + bv, 0.f);
            tls[wv * 16 + q * 4 + r][ct * 16 + m] = f2bf(v);
        }
    }
    __syncthreads();
    const long base_row = (long)blockIdx.x * 64;
#pragma unroll
    for (int it = 0; it < 4; ++it) {
        int chunk = threadIdx.x + it * 256;   // 0..1023
        int row = chunk >> 4;
        int c8 = (chunk & 15) * 8;
        *(uint4*)(outb + (base_row + row) * 128 + c8) = *(const uint4*)(&tls[row][c8]);
    }
}

// ---------------- global mean pool (two-stage, grid-parallel) ----------------

__global__ __launch_bounds__(128) void pool1_kernel(
    const u16* __restrict__ h2b, const int* __restrict__ batch,
    float* __restrict__ acc, int N, int rows_per_block)
{
    int c = threadIdx.x;
    int r0 = blockIdx.x * rows_per_block;
    if (r0 >= N) return;
    int r1 = r0 + rows_per_block;
    if (r1 > N) r1 = N;
    int cur = batch[r0];
    float sum = 0.f;
    for (int r = r0; r < r1; ++r) {
        int g = batch[r];
        float v = bf2f((u32)h2b[(long)r * 128 + c]);
        if (g != cur) {
            atomicAdd(&acc[cur * 128 + c], sum);
            sum = 0.f;
            cur = g;
        }
        sum += v;
    }
    atomicAdd(&acc[cur * 128 + c], sum);
}

__global__ __launch_bounds__(128) void pool2_kernel(
    const float* __restrict__ acc, const int* __restrict__ batch,
    float* __restrict__ out, int n)
{
    int g = blockIdx.x;
    int c = threadIdx.x;
    int lo = 0, hi = n;
    while (lo < hi) { int mid = (lo + hi) >> 1; if (batch[mid] < g) lo = mid + 1; else hi = mid; }
    int s = lo;
    lo = s; hi = n;
    while (lo < hi) { int mid = (lo + hi) >> 1; if (batch[mid] < g + 1) lo = mid + 1; else hi = mid; }
    int cnt = lo - s;
    out[g * 128 + c] = acc[g * 128 + c] / (float)(cnt > 0 ? cnt : 1);
}

// ---------------- launch ----------------
extern "C" void kernel_launch(void* const* d_in, const int* in_sizes, int n_in,
                              void* d_out, int out_size, void* d_ws, size_t ws_size,
                              hipStream_t stream)
{
    const float* x      = (const float*)d_in[0];
    const int*   ei     = (const int*)d_in[1];
    const float* eattr  = (const float*)d_in[2];
    const int*   batch  = (const int*)d_in[3];
    const float* ne_w   = (const float*)d_in[4];
    const float* ne_b   = (const float*)d_in[5];
    const float* ee_w   = (const float*)d_in[6];
    const float* ee_b   = (const float*)d_in[7];
    const float* lin1_w = (const float*)d_in[8];
    const float* lin1_b = (const float*)d_in[9];
    const float* w11    = (const float*)d_in[10];
    const float* b11    = (const float*)d_in[11];
    const float* w12    = (const float*)d_in[12];
    const float* b12    = (const float*)d_in[13];
    const float* lin2_w = (const float*)d_in[14];
    const float* lin2_b = (const float*)d_in[15];
    const float* w21    = (const float*)d_in[16];
    const float* b21    = (const float*)d_in[17];
    const float* w22    = (const float*)d_in[18];
    const float* b22    = (const float*)d_in[19];

    const int N = in_sizes[0];
    const int E = in_sizes[2];
    const int G = out_size / 128;
    const int Npad = ((N + 63) / 64) * 64;
    const int* esrc = ei;
    const int* edst = ei + E;

    char* p = (char*)d_ws;
    auto alloc = [&](size_t bytes) -> void* {
        void* r = (void*)p;
        p += (bytes + 255) & ~(size_t)255;
        return r;
    };
    float* u1 = (float*)alloc(128 * 4);
    float* C1 = (float*)alloc(128 * 4);
    float* u2 = (float*)alloc(128 * 4);
    float* C2 = (float*)alloc(128 * 4);
    int* deg    = (int*)alloc((size_t)N * 4);
    int* incl   = (int*)alloc((size_t)N * 4);
    int* bsum   = (int*)alloc(4096);
    int* boff   = (int*)alloc(4096);
    int* rowptr = (int*)alloc(((size_t)N + 1) * 4);
    int* cursor = (int*)alloc((size_t)N * 4);
    int2* edges = (int2*)alloc((size_t)E * 8);
    u16* w11hi = (u16*)alloc(16384 * 2);
    u16* w11lo = (u16*)alloc(16384 * 2);
    u16* w12hi = (u16*)alloc(16384 * 2);
    u16* w12lo = (u16*)alloc(16384 * 2);
    u16* w21hi = (u16*)alloc(16384 * 2);
    u16* w21lo = (u16*)alloc(16384 * 2);
    u16* w22hi = (u16*)alloc(16384 * 2);
    u16* w22lo = (u16*)alloc(16384 * 2);
    u16* bufA = (u16*)alloc((size_t)Npad * 128 * 2);
    u16* bufB = (u16*)alloc((size_t)Npad * 128 * 2);
    float* poolacc = (float*)alloc((size_t)G * 128 * 4);

    const int nbScan = (N + 1023) / 1024;

    hipMemsetAsync(deg, 0, (size_t)N * 4, stream);
    hipMemsetAsync(poolacc, 0, (size_t)G * 128 * 4, stream);
    consts_kernel<<<1, 128, 0, stream>>>(ne_b, ee_w, ee_b, lin1_w, lin1_b, lin2_w, lin2_b,
                                         u1, C1, u2, C2);
    prepack_kernel<<<64, 256, 0, stream>>>(w11, w11hi, w11lo);
    prepack_kernel<<<64, 256, 0, stream>>>(w12, w12hi, w12lo);
    prepack_kernel<<<64, 256, 0, stream>>>(w21, w21hi, w21lo);
    prepack_kernel<<<64, 256, 0, stream>>>(w22, w22hi, w22lo);

    count_kernel<<<(E + 255) / 256, 256, 0, stream>>>(edst, deg, E);
    scan1_kernel<<<nbScan, 1024, 0, stream>>>(deg, incl, bsum, N);
    scan2_kernel<<<1, 1024, 0, stream>>>(bsum, boff, nbScan);
    scan3_kernel<<<nbScan, 1024, 0, stream>>>(deg, incl, boff, rowptr, cursor, N);
    scatter_kernel<<<(E + 255) / 256, 256, 0, stream>>>(esrc, edst, eattr, cursor, edges, E);

    pull1_kernel<<<(N + 3) / 4, 256, 0, stream>>>(x, rowptr, edges, ne_w, ne_b, u1, C1,
                                                  bufA, N);
    mlp_kernel<<<Npad / 64, 256, 0, stream>>>(bufA, w11hi, w11lo, w12hi, w12lo, b11, b12, bufB);
    pull2_kernel<<<(N + 3) / 4, 256, 0, stream>>>(bufB, rowptr, edges, u2, C2, bufA, N);
    mlp_kernel<<<Npad / 64, 256, 0, stream>>>(bufA, w21hi, w21lo, w22hi, w22lo, b21, b22, bufB);

    const int rows_per_block = 128;
    pool1_kernel<<<(N + rows_per_block - 1) / rows_per_block, 128, 0, stream>>>(
        bufB, batch, poolacc, N, rows_per_block);
    pool2_kernel<<<G, 128, 0, stream>>>(poolacc, batch, (float*)d_out, N);
}

// Round 4
// 558.866 us; speedup vs baseline: 1.4983x; 1.0093x over previous
//
#include <hip/hip_runtime.h>

typedef unsigned short u16;
typedef unsigned int u32;
typedef __bf16 bfrag __attribute__((ext_vector_type(8)));
typedef float f32x4 __attribute__((ext_vector_type(4)));

__device__ __forceinline__ u16 f2bf(float f) {
    u32 u = __float_as_uint(f);
    u32 r = (u + 0x7FFFu + ((u >> 16) & 1u)) >> 16;
    return (u16)r;
}
__device__ __forceinline__ float bf2f(u32 h) {
    return __uint_as_float(h << 16);
}

// ---------------- small precompute kernels ----------------

__global__ __launch_bounds__(128) void consts_kernel(
    const float* __restrict__ ne_b, const float* __restrict__ ee_w, const float* __restrict__ ee_b,
    const float* __restrict__ lin1_w, const float* __restrict__ lin1_b,
    const float* __restrict__ lin2_w, const float* __restrict__ lin2_b,
    float* __restrict__ u1, float* __restrict__ C1, float* __restrict__ u2, float* __restrict__ C2)
{
    int c = threadIdx.x;
    float s1 = 0.f, t1 = 0.f, s2 = 0.f, t2 = 0.f;
    for (int k = 0; k < 128; ++k) {
        float w1 = lin1_w[k * 128 + c];
        float w2 = lin2_w[k * 128 + c];
        float ew = ee_w[k], eb = ee_b[k];
        s1 = fmaf(ew, w1, s1); t1 = fmaf(eb, w1, t1);
        s2 = fmaf(ew, w2, s2); t2 = fmaf(eb, w2, t2);
    }
    u1[c] = s1; C1[c] = t1 + lin1_b[c] + ne_b[c];
    u2[c] = s2; C2[c] = t2 + lin2_b[c];
}

// Pack W [128x128] fp32 row-major -> MFMA B-fragment order, split into bf16 hi + lo.
__global__ __launch_bounds__(256) void prepack_kernel(
    const float* __restrict__ w, u16* __restrict__ hi, u16* __restrict__ lo)
{
    int o = blockIdx.x * 256 + threadIdx.x;   // 0..16383
    int j = o & 7;
    int lane = (o >> 3) & 63;
    int ct = (o >> 9) & 7;
    int ks = o >> 12;
    int k = ks * 32 + ((lane >> 4) * 8) + j;
    int c = ct * 16 + (lane & 15);
    float v = w[k * 128 + c];
    u16 h = f2bf(v);
    float vh = bf2f(h);
    u16 l = f2bf(v - vh);
    hi[o] = h; lo[o] = l;
}

// ---------------- CSR build ----------------

// 4 edges per thread: independent non-returning atomics pipeline freely
__global__ __launch_bounds__(256) void count_kernel(
    const int* __restrict__ dst, int* __restrict__ deg, int E)
{
    int base = blockIdx.x * 1024 + threadIdx.x;
#pragma unroll
    for (int k = 0; k < 4; ++k) {
        int e = base + k * 256;
        if (e < E) atomicAdd(&deg[dst[e]], 1);
    }
}

__global__ __launch_bounds__(1024) void scan1_kernel(
    const int* __restrict__ deg, int* __restrict__ incl, int* __restrict__ bsum, int n)
{
    __shared__ int buf[1024];
    int i = blockIdx.x * 1024 + threadIdx.x;
    int v = (i < n) ? deg[i] : 0;
    buf[threadIdx.x] = v;
    __syncthreads();
    for (int off = 1; off < 1024; off <<= 1) {
        int t = (threadIdx.x >= off) ? buf[threadIdx.x - off] : 0;
        __syncthreads();
        buf[threadIdx.x] += t;
        __syncthreads();
    }
    if (i < n) incl[i] = buf[threadIdx.x];
    if (threadIdx.x == 1023) bsum[blockIdx.x] = buf[1023];
}

// parallel single-block exclusive scan of block sums (nb <= 1024)
__global__ __launch_bounds__(1024) void scan2_kernel(
    const int* __restrict__ bsum, int* __restrict__ boff, int nb)
{
    __shared__ int buf[1024];
    int i = threadIdx.x;
    int v = (i < nb) ? bsum[i] : 0;
    buf[i] = v;
    __syncthreads();
    for (int off = 1; off < 1024; off <<= 1) {
        int t = (i >= off) ? buf[i - off] : 0;
        __syncthreads();
        buf[i] += t;
        __syncthreads();
    }
    if (i < nb) boff[i] = buf[i] - v;
}

__global__ __launch_bounds__(1024) void scan3_kernel(
    const int* __restrict__ deg, const int* __restrict__ incl, const int* __restrict__ boff,
    int* __restrict__ rowptr, int* __restrict__ cursor, int n)
{
    int i = blockIdx.x * 1024 + threadIdx.x;
    if (i < n) {
        int inc = boff[blockIdx.x] + incl[i];
        int ex = inc - deg[i];
        rowptr[i] = ex;
        cursor[i] = ex;
        if (i == n - 1) rowptr[n] = inc;
    }
}

// 4 edges per thread: 4 coalesced load groups, 4 independent returning
// atomics in flight, then 4 scatter writes
__global__ __launch_bounds__(256) void scatter_kernel(
    const int* __restrict__ src, const int* __restrict__ dst, const float* __restrict__ eattr,
    int* __restrict__ cursor, int2* __restrict__ edges, int E)
{
    int base = blockIdx.x * 1024 + threadIdx.x;
    int d[4], s[4], av[4];
    bool ok[4];
#pragma unroll
    for (int k = 0; k < 4; ++k) {
        int e = base + k * 256;
        ok[k] = e < E;
        if (ok[k]) {
            d[k] = dst[e];
            s[k] = src[e];
            av[k] = __float_as_int(eattr[e]);
        }
    }
    int p[4];
#pragma unroll
    for (int k = 0; k < 4; ++k) {
        if (ok[k]) p[k] = atomicAdd(&cursor[d[k]], 1);
    }
#pragma unroll
    for (int k = 0; k < 4; ++k) {
        if (ok[k]) edges[p[k]] = make_int2(s[k], av[k]);
    }
}

// ---------------- pull aggregation (8-deep MLP unroll) ----------------

__global__ __launch_bounds__(256) void pull1_kernel(
    const float* __restrict__ x,
    const int* __restrict__ rowptr, const int2* __restrict__ edges,
    const float* __restrict__ ne_w, const float* __restrict__ ne_b,
    const float* __restrict__ u1, const float* __restrict__ C1,
    u16* __restrict__ zb, int N)
{
    int lane = threadIdx.x & 63;
    int node = blockIdx.x * 4 + (threadIdx.x >> 6);
    if (node >= N) return;
    float2 A  = *(const float2*)(ne_w + 2 * lane);
    float2 Bv = *(const float2*)(u1   + 2 * lane);
    float2 Cv = *(const float2*)(C1   + 2 * lane);
    float2 nb = *(const float2*)(ne_b + 2 * lane);
    int jb = rowptr[node], je = rowptr[node + 1];
    float a0 = 0.f, a1 = 0.f;
    int j = jb;
    for (; j + 8 <= je; j += 8) {
        float xs[8], av[8];
#pragma unroll
        for (int t = 0; t < 8; ++t) {
            int2 ep = edges[j + t];
            av[t] = __int_as_float(ep.y);
            xs[t] = x[ep.x];
        }
#pragma unroll
        for (int t = 0; t < 8; ++t) {
            float m0 = fmaf(xs[t], A.x, fmaf(av[t], Bv.x, Cv.x));
            float m1 = fmaf(xs[t], A.y, fmaf(av[t], Bv.y, Cv.y));
            a0 += fmaxf(m0, 0.f);
            a1 += fmaxf(m1, 0.f);
        }
    }
    for (; j < je; ++j) {
        int2 ep = edges[j];
        float av = __int_as_float(ep.y);
        float xs = x[ep.x];
        float m0 = fmaf(xs, A.x, fmaf(av, Bv.x, Cv.x));
        float m1 = fmaf(xs, A.y, fmaf(av, Bv.y, Cv.y));
        a0 += fmaxf(m0, 0.f);
        a1 += fmaxf(m1, 0.f);
    }
    float xn = x[node];
    float z0 = fmaf(xn, A.x, nb.x) + a0;
    float z1 = fmaf(xn, A.y, nb.y) + a1;
    ((u32*)(zb + (long)node * 128))[lane] = (u32)f2bf(z0) | ((u32)f2bf(z1) << 16);
}

__global__ __launch_bounds__(256) void pull2_kernel(
    const u16* __restrict__ h1b,
    const int* __restrict__ rowptr, const int2* __restrict__ edges,
    const float* __restrict__ u2, const float* __restrict__ C2,
    u16* __restrict__ zb2, int N)
{
    int lane = threadIdx.x & 63;
    int node = blockIdx.x * 4 + (threadIdx.x >> 6);
    if (node >= N) return;
    float2 Bv = *(const float2*)(u2 + 2 * lane);
    float2 Cv = *(const float2*)(C2 + 2 * lane);
    int jb = rowptr[node], je = rowptr[node + 1];
    float a0 = 0.f, a1 = 0.f;
    int j = jb;
    for (; j + 8 <= je; j += 8) {
        u32 hv[8];
        float av[8];
#pragma unroll
        for (int t = 0; t < 8; ++t) {
            int2 ep = edges[j + t];
            av[t] = __int_as_float(ep.y);
            hv[t] = ((const u32*)(h1b + (long)ep.x * 128))[lane];
        }
#pragma unroll
        for (int t = 0; t < 8; ++t) {
            float m0 = bf2f(hv[t] & 0xFFFFu) + fmaf(av[t], Bv.x, Cv.x);
            float m1 = bf2f(hv[t] >> 16) + fmaf(av[t], Bv.y, Cv.y);
            a0 += fmaxf(m0, 0.f);
            a1 += fmaxf(m1, 0.f);
        }
    }
    for (; j < je; ++j) {
        int2 ep = edges[j];
        float av = __int_as_float(ep.y);
        u32 hv = ((const u32*)(h1b + (long)ep.x * 128))[lane];
        float m0 = bf2f(hv & 0xFFFFu) + fmaf(av, Bv.x, Cv.x);
        float m1 = bf2f(hv >> 16) + fmaf(av, Bv.y, Cv.y);
        a0 += fmaxf(m0, 0.f);
        a1 += fmaxf(m1, 0.f);
    }
    u32 hn = ((const u32*)(h1b + (long)node * 128))[lane];
    float z0 = bf2f(hn & 0xFFFFu) + a0;
    float z1 = bf2f(hn >> 16) + a1;
    ((u32*)(zb2 + (long)node * 128))[lane] = (u32)f2bf(z0) | ((u32)f2bf(z1) << 16);
}

// ---------------- fused 2-GEMM node MLP (bf16 MFMA, split weights) ----------------
__global__ __launch_bounds__(256) void mlp_kernel(
    const u16* __restrict__ zb,
    const u16* __restrict__ w1hi, const u16* __restrict__ w1lo,
    const u16* __restrict__ w2hi, const u16* __restrict__ w2lo,
    const float* __restrict__ b1, const float* __restrict__ b2,
    u16* __restrict__ outb)
{
    __shared__ __align__(16) u16 tls[64][136];
    const int lane = threadIdx.x & 63;
    const int wv = threadIdx.x >> 6;
    const int m = lane & 15;
    const int q = lane >> 4;
    const int ko = q * 8;
    const long tile_row = (long)blockIdx.x * 64 + wv * 16;

    f32x4 acc[8];
#pragma unroll
    for (int ct = 0; ct < 8; ++ct) acc[ct] = (f32x4){0.f, 0.f, 0.f, 0.f};

#pragma unroll
    for (int ks = 0; ks < 4; ++ks) {
        bfrag a = *(const bfrag*)(zb + (tile_row + m) * 128 + ks * 32 + ko);
#pragma unroll
        for (int ct = 0; ct < 8; ++ct) {
            const int off = (((ks * 8 + ct) * 64) + lane) * 8;
            bfrag bh = *(const bfrag*)(w1hi + off);
            bfrag bl = *(const bfrag*)(w1lo + off);
            acc[ct] = __builtin_amdgcn_mfma_f32_16x16x32_bf16(a, bh, acc[ct], 0, 0, 0);
            acc[ct] = __builtin_amdgcn_mfma_f32_16x16x32_bf16(a, bl, acc[ct], 0, 0, 0);
        }
    }
#pragma unroll
    for (int ct = 0; ct < 8; ++ct) {
        float bv = b1[ct * 16 + m];
#pragma unroll
        for (int r = 0; r < 4; ++r) {
            float v = fmaxf(acc[ct][r] + bv, 0.f);
            tls[wv * 16 + q * 4 + r][ct * 16 + m] = f2bf(v);
        }
    }
    __syncthreads();

    f32x4 acc2[8];
#pragma unroll
    for (int ct = 0; ct < 8; ++ct) acc2[ct] = (f32x4){0.f, 0.f, 0.f, 0.f};

#pragma unroll
    for (int ks = 0; ks < 4; ++ks) {
        bfrag a = *(const bfrag*)(&tls[wv * 16 + m][ks * 32 + ko]);
#pragma unroll
        for (int ct = 0; ct < 8; ++ct) {
            const int off = (((ks * 8 + ct) * 64) + lane) * 8;
            bfrag bh = *(const bfrag*)(w2hi + off);
            bfrag bl = *(const bfrag*)(w2lo + off);
            acc2[ct] = __builtin_amdgcn_mfma_f32_16x16x32_bf16(a, bh, acc2[ct], 0, 0, 0);
            acc2[ct] = __builtin_amdgcn_mfma_f32_16x16x32_bf16(a, bl, acc2[ct], 0, 0, 0);
        }
    }
#pragma unroll
    for (int ct = 0; ct < 8; ++ct) {
        float bv = b2[ct * 16 + m];
#pragma unroll
        for (int r = 0; r < 4; ++r) {
            float v = fmaxf(acc2[ct][r] + bv, 0.f);
            tls[wv * 16 + q * 4 + r][ct * 16 + m] = f2bf(v);
        }
    }
    __syncthreads();
    const long base_row = (long)blockIdx.x * 64;
#pragma unroll
    for (int it = 0; it < 4; ++it) {
        int chunk = threadIdx.x + it * 256;   // 0..1023
        int row = chunk >> 4;
        int c8 = (chunk & 15) * 8;
        *(uint4*)(outb + (base_row + row) * 128 + c8) = *(const uint4*)(&tls[row][c8]);
    }
}

// ---------------- global mean pool (two-stage, grid-parallel) ----------------

__global__ __launch_bounds__(128) void pool1_kernel(
    const u16* __restrict__ h2b, const int* __restrict__ batch,
    float* __restrict__ acc, int N, int rows_per_block)
{
    int c = threadIdx.x;
    int r0 = blockIdx.x * rows_per_block;
    if (r0 >= N) return;
    int r1 = r0 + rows_per_block;
    if (r1 > N) r1 = N;
    int cur = batch[r0];
    float sum = 0.f;
    for (int r = r0; r < r1; ++r) {
        int g = batch[r];
        float v = bf2f((u32)h2b[(long)r * 128 + c]);
        if (g != cur) {
            atomicAdd(&acc[cur * 128 + c], sum);
            sum = 0.f;
            cur = g;
        }
        sum += v;
    }
    atomicAdd(&acc[cur * 128 + c], sum);
}

__global__ __launch_bounds__(128) void pool2_kernel(
    const float* __restrict__ acc, const int* __restrict__ batch,
    float* __restrict__ out, int n)
{
    int g = blockIdx.x;
    int c = threadIdx.x;
    int lo = 0, hi = n;
    while (lo < hi) { int mid = (lo + hi) >> 1; if (batch[mid] < g) lo = mid + 1; else hi = mid; }
    int s = lo;
    lo = s; hi = n;
    while (lo < hi) { int mid = (lo + hi) >> 1; if (batch[mid] < g + 1) lo = mid + 1; else hi = mid; }
    int cnt = lo - s;
    out[g * 128 + c] = acc[g * 128 + c] / (float)(cnt > 0 ? cnt : 1);
}

// ---------------- launch ----------------
extern "C" void kernel_launch(void* const* d_in, const int* in_sizes, int n_in,
                              void* d_out, int out_size, void* d_ws, size_t ws_size,
                              hipStream_t stream)
{
    const float* x      = (const float*)d_in[0];
    const int*   ei     = (const int*)d_in[1];
    const float* eattr  = (const float*)d_in[2];
    const int*   batch  = (const int*)d_in[3];
    const float* ne_w   = (const float*)d_in[4];
    const float* ne_b   = (const float*)d_in[5];
    const float* ee_w   = (const float*)d_in[6];
    const float* ee_b   = (const float*)d_in[7];
    const float* lin1_w = (const float*)d_in[8];
    const float* lin1_b = (const float*)d_in[9];
    const float* w11    = (const float*)d_in[10];
    const float* b11    = (const float*)d_in[11];
    const float* w12    = (const float*)d_in[12];
    const float* b12    = (const float*)d_in[13];
    const float* lin2_w = (const float*)d_in[14];
    const float* lin2_b = (const float*)d_in[15];
    const float* w21    = (const float*)d_in[16];
    const float* b21    = (const float*)d_in[17];
    const float* w22    = (const float*)d_in[18];
    const float* b22    = (const float*)d_in[19];

    const int N = in_sizes[0];
    const int E = in_sizes[2];
    const int G = out_size / 128;
    const int Npad = ((N + 63) / 64) * 64;
    const int* esrc = ei;
    const int* edst = ei + E;

    char* p = (char*)d_ws;
    auto alloc = [&](size_t bytes) -> void* {
        void* r = (void*)p;
        p += (bytes + 255) & ~(size_t)255;
        return r;
    };
    float* u1 = (float*)alloc(128 * 4);
    float* C1 = (float*)alloc(128 * 4);
    float* u2 = (float*)alloc(128 * 4);
    float* C2 = (float*)alloc(128 * 4);
    int* deg    = (int*)alloc((size_t)N * 4);
    int* incl   = (int*)alloc((size_t)N * 4);
    int* bsum   = (int*)alloc(4096);
    int* boff   = (int*)alloc(4096);
    int* rowptr = (int*)alloc(((size_t)N + 1) * 4);
    int* cursor = (int*)alloc((size_t)N * 4);
    int2* edges = (int2*)alloc((size_t)E * 8);
    u16* w11hi = (u16*)alloc(16384 * 2);
    u16* w11lo = (u16*)alloc(16384 * 2);
    u16* w12hi = (u16*)alloc(16384 * 2);
    u16* w12lo = (u16*)alloc(16384 * 2);
    u16* w21hi = (u16*)alloc(16384 * 2);
    u16* w21lo = (u16*)alloc(16384 * 2);
    u16* w22hi = (u16*)alloc(16384 * 2);
    u16* w22lo = (u16*)alloc(16384 * 2);
    u16* bufA = (u16*)alloc((size_t)Npad * 128 * 2);
    u16* bufB = (u16*)alloc((size_t)Npad * 128 * 2);
    float* poolacc = (float*)alloc((size_t)G * 128 * 4);

    const int nbScan = (N + 1023) / 1024;

    hipMemsetAsync(deg, 0, (size_t)N * 4, stream);
    hipMemsetAsync(poolacc, 0, (size_t)G * 128 * 4, stream);
    consts_kernel<<<1, 128, 0, stream>>>(ne_b, ee_w, ee_b, lin1_w, lin1_b, lin2_w, lin2_b,
                                         u1, C1, u2, C2);
    prepack_kernel<<<64, 256, 0, stream>>>(w11, w11hi, w11lo);
    prepack_kernel<<<64, 256, 0, stream>>>(w12, w12hi, w12lo);
    prepack_kernel<<<64, 256, 0, stream>>>(w21, w21hi, w21lo);
    prepack_kernel<<<64, 256, 0, stream>>>(w22, w22hi, w22lo);

    count_kernel<<<(E + 1023) / 1024, 256, 0, stream>>>(edst, deg, E);
    scan1_kernel<<<nbScan, 1024, 0, stream>>>(deg, incl, bsum, N);
    scan2_kernel<<<1, 1024, 0, stream>>>(bsum, boff, nbScan);
    scan3_kernel<<<nbScan, 1024, 0, stream>>>(deg, incl, boff, rowptr, cursor, N);
    scatter_kernel<<<(E + 1023) / 1024, 256, 0, stream>>>(esrc, edst, eattr, cursor, edges, E);

    pull1_kernel<<<(N + 3) / 4, 256, 0, stream>>>(x, rowptr, edges, ne_w, ne_b, u1, C1,
                                                  bufA, N);
    mlp_kernel<<<Npad / 64, 256, 0, stream>>>(bufA, w11hi, w11lo, w12hi, w12lo, b11, b12, bufB);
    pull2_kernel<<<(N + 3) / 4, 256, 0, stream>>>(bufB, rowptr, edges, u2, C2, bufA, N);
    mlp_kernel<<<Npad / 64, 256, 0, stream>>>(bufA, w21hi, w21lo, w22hi, w22lo, b21, b22, bufB);

    const int rows_per_block = 128;
    pool1_kernel<<<(N + rows_per_block - 1) / rows_per_block, 128, 0, stream>>>(
        bufB, batch, poolacc, N, rows_per_block);
    pool2_kernel<<<G, 128, 0, stream>>>(poolacc, batch, (float*)d_out, N);
}

// Round 5
// 505.103 us; speedup vs baseline: 1.6578x; 1.1064x over previous
//
#include <hip/hip_runtime.h>

typedef unsigned short u16;
typedef unsigned int u32;
typedef __bf16 bfrag __attribute__((ext_vector_type(8)));
typedef float f32x4 __attribute__((ext_vector_type(4)));

__device__ __forceinline__ u16 f2bf(float f) {
    u32 u = __float_as_uint(f);
    u32 r = (u + 0x7FFFu + ((u >> 16) & 1u)) >> 16;
    return (u16)r;
}
__device__ __forceinline__ float bf2f(u32 h) {
    return __uint_as_float(h << 16);
}

// ---------------- small precompute kernels ----------------

__global__ __launch_bounds__(128) void consts_kernel(
    const float* __restrict__ ne_b, const float* __restrict__ ee_w, const float* __restrict__ ee_b,
    const float* __restrict__ lin1_w, const float* __restrict__ lin1_b,
    const float* __restrict__ lin2_w, const float* __restrict__ lin2_b,
    float* __restrict__ u1, float* __restrict__ C1, float* __restrict__ u2, float* __restrict__ C2)
{
    int c = threadIdx.x;
    float s1 = 0.f, t1 = 0.f, s2 = 0.f, t2 = 0.f;
    for (int k = 0; k < 128; ++k) {
        float w1 = lin1_w[k * 128 + c];
        float w2 = lin2_w[k * 128 + c];
        float ew = ee_w[k], eb = ee_b[k];
        s1 = fmaf(ew, w1, s1); t1 = fmaf(eb, w1, t1);
        s2 = fmaf(ew, w2, s2); t2 = fmaf(eb, w2, t2);
    }
    u1[c] = s1; C1[c] = t1 + lin1_b[c] + ne_b[c];
    u2[c] = s2; C2[c] = t2 + lin2_b[c];
}

// Pack W [128x128] fp32 row-major -> MFMA B-fragment order, split into bf16 hi + lo.
__global__ __launch_bounds__(256) void prepack_kernel(
    const float* __restrict__ w, u16* __restrict__ hi, u16* __restrict__ lo)
{
    int o = blockIdx.x * 256 + threadIdx.x;   // 0..16383
    int j = o & 7;
    int lane = (o >> 3) & 63;
    int ct = (o >> 9) & 7;
    int ks = o >> 12;
    int k = ks * 32 + ((lane >> 4) * 8) + j;
    int c = ct * 16 + (lane & 15);
    float v = w[k * 128 + c];
    u16 h = f2bf(v);
    float vh = bf2f(h);
    u16 l = f2bf(v - vh);
    hi[o] = h; lo[o] = l;
}

// ---------------- CSR build ----------------

__global__ __launch_bounds__(256) void count_kernel(
    const int* __restrict__ dst, int* __restrict__ deg, int E)
{
    int base = blockIdx.x * 1024 + threadIdx.x;
#pragma unroll
    for (int k = 0; k < 4; ++k) {
        int e = base + k * 256;
        if (e < E) atomicAdd(&deg[dst[e]], 1);
    }
}

__global__ __launch_bounds__(1024) void scan1_kernel(
    const int* __restrict__ deg, int* __restrict__ incl, int* __restrict__ bsum, int n)
{
    __shared__ int buf[1024];
    int i = blockIdx.x * 1024 + threadIdx.x;
    int v = (i < n) ? deg[i] : 0;
    buf[threadIdx.x] = v;
    __syncthreads();
    for (int off = 1; off < 1024; off <<= 1) {
        int t = (threadIdx.x >= off) ? buf[threadIdx.x - off] : 0;
        __syncthreads();
        buf[threadIdx.x] += t;
        __syncthreads();
    }
    if (i < n) incl[i] = buf[threadIdx.x];
    if (threadIdx.x == 1023) bsum[blockIdx.x] = buf[1023];
}

__global__ __launch_bounds__(1024) void scan2_kernel(
    const int* __restrict__ bsum, int* __restrict__ boff, int nb)
{
    __shared__ int buf[1024];
    int i = threadIdx.x;
    int v = (i < nb) ? bsum[i] : 0;
    buf[i] = v;
    __syncthreads();
    for (int off = 1; off < 1024; off <<= 1) {
        int t = (i >= off) ? buf[i - off] : 0;
        __syncthreads();
        buf[i] += t;
        __syncthreads();
    }
    if (i < nb) boff[i] = buf[i] - v;
}

__global__ __launch_bounds__(1024) void scan3_kernel(
    const int* __restrict__ deg, const int* __restrict__ incl, const int* __restrict__ boff,
    int* __restrict__ rowptr, int* __restrict__ cursor, int n)
{
    int i = blockIdx.x * 1024 + threadIdx.x;
    if (i < n) {
        int inc = boff[blockIdx.x] + incl[i];
        int ex = inc - deg[i];
        rowptr[i] = ex;
        cursor[i] = ex;
        if (i == n - 1) rowptr[n] = inc;
    }
}

// ---------------- two-level edge permutation (bucket = dst >> 9) ----------------

// bstart[b] = rowptr[min(b*512, N)]; bucket_cursor[b] = same (phase-3 claim cursor)
__global__ __launch_bounds__(256) void bucket_init_kernel(
    const int* __restrict__ rowptr, int* __restrict__ bstart, int* __restrict__ bucket_cursor,
    int N, int nb)
{
    int b = blockIdx.x * 256 + threadIdx.x;
    if (b <= nb) {
        int node = b << 9;
        if (node > N) node = N;
        int v = rowptr[node];
        bstart[b] = v;
        if (b < nb) bucket_cursor[b] = v;
    }
}

// Phase 3: block-local counting sort by bucket, coalesced run flush.
// 4096 edges/block, 1024 threads. LDS ~52 KB.
__global__ __launch_bounds__(1024) void bin_kernel(
    const int* __restrict__ src, const int* __restrict__ dst, const float* __restrict__ eattr,
    int* __restrict__ bucket_cursor,
    int2* __restrict__ binned, u16* __restrict__ binned_dlo, int E, int nb)
{
    __shared__ int hist[256];
    __shared__ int cnt[256];
    __shared__ int basel[256];
    __shared__ int gbase[256];
    __shared__ int2 stage[4096];
    __shared__ int sdst[4096];
    const int tid = threadIdx.x;
    const int e0 = blockIdx.x * 4096;
    const int valid = min(4096, E - e0);

    if (tid < 256) hist[tid] = 0;
    __syncthreads();

    int d[4], s[4], a[4], rk[4];
    bool ok[4];
#pragma unroll
    for (int k = 0; k < 4; ++k) {
        int e = e0 + k * 1024 + tid;
        ok[k] = e < E;
        if (ok[k]) {
            d[k] = dst[e];
            s[k] = src[e];
            a[k] = __float_as_int(eattr[e]);
        }
    }
#pragma unroll
    for (int k = 0; k < 4; ++k) {
        if (ok[k]) rk[k] = atomicAdd(&hist[d[k] >> 9], 1);
    }
    __syncthreads();
    if (tid < 256) { cnt[tid] = hist[tid]; basel[tid] = hist[tid]; }
    __syncthreads();
    // inclusive scan over 256 buckets
    for (int off = 1; off < 256; off <<= 1) {
        int t = 0;
        if (tid < 256 && tid >= off) t = basel[tid - off];
        __syncthreads();
        if (tid < 256) basel[tid] += t;
        __syncthreads();
    }
    // to exclusive; claim global space per bucket
    if (tid < 256) basel[tid] -= cnt[tid];
    __syncthreads();
    if (tid < nb && cnt[tid] > 0) gbase[tid] = atomicAdd(&bucket_cursor[tid], cnt[tid]);
    __syncthreads();
    // stage bucket-sorted
#pragma unroll
    for (int k = 0; k < 4; ++k) {
        if (ok[k]) {
            int pos = basel[d[k] >> 9] + rk[k];
            stage[pos] = make_int2(s[k], a[k]);
            sdst[pos] = d[k];
        }
    }
    __syncthreads();
    // coalesced flush of runs
    for (int i = tid; i < valid; i += 1024) {
        int dd = sdst[i];
        int b = dd >> 9;
        int g = gbase[b] + (i - basel[b]);
        binned[g] = stage[i];
        binned_dlo[g] = (u16)(dd & 511);
    }
}

// Phase 4: one block per bucket; final scatter into block-exclusive CSR region.
__global__ __launch_bounds__(1024) void fine_kernel(
    const int2* __restrict__ binned, const u16* __restrict__ binned_dlo,
    const int* __restrict__ bstart,
    int* __restrict__ cursor, int2* __restrict__ edges)
{
    int b = blockIdx.x;
    int s0 = bstart[b], s1 = bstart[b + 1];
    int dbase = b << 9;
    for (int i = s0 + threadIdx.x; i < s1; i += 1024) {
        int2 ed = binned[i];
        int dstn = dbase + (int)binned_dlo[i];
        int p = atomicAdd(&cursor[dstn], 1);
        edges[p] = ed;
    }
}

// ---------------- pull aggregation (8-deep MLP unroll) ----------------

__global__ __launch_bounds__(256) void pull1_kernel(
    const float* __restrict__ x,
    const int* __restrict__ rowptr, const int2* __restrict__ edges,
    const float* __restrict__ ne_w, const float* __restrict__ ne_b,
    const float* __restrict__ u1, const float* __restrict__ C1,
    u16* __restrict__ zb, int N)
{
    int lane = threadIdx.x & 63;
    int node = blockIdx.x * 4 + (threadIdx.x >> 6);
    if (node >= N) return;
    float2 A  = *(const float2*)(ne_w + 2 * lane);
    float2 Bv = *(const float2*)(u1   + 2 * lane);
    float2 Cv = *(const float2*)(C1   + 2 * lane);
    float2 nb = *(const float2*)(ne_b + 2 * lane);
    int jb = rowptr[node], je = rowptr[node + 1];
    float a0 = 0.f, a1 = 0.f;
    int j = jb;
    for (; j + 8 <= je; j += 8) {
        float xs[8], av[8];
#pragma unroll
        for (int t = 0; t < 8; ++t) {
            int2 ep = edges[j + t];
            av[t] = __int_as_float(ep.y);
            xs[t] = x[ep.x];
        }
#pragma unroll
        for (int t = 0; t < 8; ++t) {
            float m0 = fmaf(xs[t], A.x, fmaf(av[t], Bv.x, Cv.x));
            float m1 = fmaf(xs[t], A.y, fmaf(av[t], Bv.y, Cv.y));
            a0 += fmaxf(m0, 0.f);
            a1 += fmaxf(m1, 0.f);
        }
    }
    for (; j < je; ++j) {
        int2 ep = edges[j];
        float av = __int_as_float(ep.y);
        float xs = x[ep.x];
        float m0 = fmaf(xs, A.x, fmaf(av, Bv.x, Cv.x));
        float m1 = fmaf(xs, A.y, fmaf(av, Bv.y, Cv.y));
        a0 += fmaxf(m0, 0.f);
        a1 += fmaxf(m1, 0.f);
    }
    float xn = x[node];
    float z0 = fmaf(xn, A.x, nb.x) + a0;
    float z1 = fmaf(xn, A.y, nb.y) + a1;
    ((u32*)(zb + (long)node * 128))[lane] = (u32)f2bf(z0) | ((u32)f2bf(z1) << 16);
}

__global__ __launch_bounds__(256) void pull2_kernel(
    const u16* __restrict__ h1b,
    const int* __restrict__ rowptr, const int2* __restrict__ edges,
    const float* __restrict__ u2, const float* __restrict__ C2,
    u16* __restrict__ zb2, int N)
{
    int lane = threadIdx.x & 63;
    int node = blockIdx.x * 4 + (threadIdx.x >> 6);
    if (node >= N) return;
    float2 Bv = *(const float2*)(u2 + 2 * lane);
    float2 Cv = *(const float2*)(C2 + 2 * lane);
    int jb = rowptr[node], je = rowptr[node + 1];
    float a0 = 0.f, a1 = 0.f;
    int j = jb;
    for (; j + 8 <= je; j += 8) {
        u32 hv[8];
        float av[8];
#pragma unroll
        for (int t = 0; t < 8; ++t) {
            int2 ep = edges[j + t];
            av[t] = __int_as_float(ep.y);
            hv[t] = ((const u32*)(h1b + (long)ep.x * 128))[lane];
        }
#pragma unroll
        for (int t = 0; t < 8; ++t) {
            float m0 = bf2f(hv[t] & 0xFFFFu) + fmaf(av[t], Bv.x, Cv.x);
            float m1 = bf2f(hv[t] >> 16) + fmaf(av[t], Bv.y, Cv.y);
            a0 += fmaxf(m0, 0.f);
            a1 += fmaxf(m1, 0.f);
        }
    }
    for (; j < je; ++j) {
        int2 ep = edges[j];
        float av = __int_as_float(ep.y);
        u32 hv = ((const u32*)(h1b + (long)ep.x * 128))[lane];
        float m0 = bf2f(hv & 0xFFFFu) + fmaf(av, Bv.x, Cv.x);
        float m1 = bf2f(hv >> 16) + fmaf(av, Bv.y, Cv.y);
        a0 += fmaxf(m0, 0.f);
        a1 += fmaxf(m1, 0.f);
    }
    u32 hn = ((const u32*)(h1b + (long)node * 128))[lane];
    float z0 = bf2f(hn & 0xFFFFu) + a0;
    float z1 = bf2f(hn >> 16) + a1;
    ((u32*)(zb2 + (long)node * 128))[lane] = (u32)f2bf(z0) | ((u32)f2bf(z1) << 16);
}

// ---------------- fused 2-GEMM node MLP (bf16 MFMA, split weights) ----------------
__global__ __launch_bounds__(256) void mlp_kernel(
    const u16* __restrict__ zb,
    const u16* __restrict__ w1hi, const u16* __restrict__ w1lo,
    const u16* __restrict__ w2hi, const u16* __restrict__ w2lo,
    const float* __restrict__ b1, const float* __restrict__ b2,
    u16* __restrict__ outb)
{
    __shared__ __align__(16) u16 tls[64][136];
    const int lane = threadIdx.x & 63;
    const int wv = threadIdx.x >> 6;
    const int m = lane & 15;
    const int q = lane >> 4;
    const int ko = q * 8;
    const long tile_row = (long)blockIdx.x * 64 + wv * 16;

    f32x4 acc[8];
#pragma unroll
    for (int ct = 0; ct < 8; ++ct) acc[ct] = (f32x4){0.f, 0.f, 0.f, 0.f};

#pragma unroll
    for (int ks = 0; ks < 4; ++ks) {
        bfrag a = *(const bfrag*)(zb + (tile_row + m) * 128 + ks * 32 + ko);
#pragma unroll
        for (int ct = 0; ct < 8; ++ct) {
            const int off = (((ks * 8 + ct) * 64) + lane) * 8;
            bfrag bh = *(const bfrag*)(w1hi + off);
            bfrag bl = *(const bfrag*)(w1lo + off);
            acc[ct] = __builtin_amdgcn_mfma_f32_16x16x32_bf16(a, bh, acc[ct], 0, 0, 0);
            acc[ct] = __builtin_amdgcn_mfma_f32_16x16x32_bf16(a, bl, acc[ct], 0, 0, 0);
        }
    }
#pragma unroll
    for (int ct = 0; ct < 8; ++ct) {
        float bv = b1[ct * 16 + m];
#pragma unroll
        for (int r = 0; r < 4; ++r) {
            float v = fmaxf(acc[ct][r] + bv, 0.f);
            tls[wv * 16 + q * 4 + r][ct * 16 + m] = f2bf(v);
        }
    }
    __syncthreads();

    f32x4 acc2[8];
#pragma unroll
    for (int ct = 0; ct < 8; ++ct) acc2[ct] = (f32x4){0.f, 0.f, 0.f, 0.f};

#pragma unroll
    for (int ks = 0; ks < 4; ++ks) {
        bfrag a = *(const bfrag*)(&tls[wv * 16 + m][ks * 32 + ko]);
#pragma unroll
        for (int ct = 0; ct < 8; ++ct) {
            const int off = (((ks * 8 + ct) * 64) + lane) * 8;
            bfrag bh = *(const bfrag*)(w2hi + off);
            bfrag bl = *(const bfrag*)(w2lo + off);
            acc2[ct] = __builtin_amdgcn_mfma_f32_16x16x32_bf16(a, bh, acc2[ct], 0, 0, 0);
            acc2[ct] = __builtin_amdgcn_mfma_f32_16x16x32_bf16(a, bl, acc2[ct], 0, 0, 0);
        }
    }
#pragma unroll
    for (int ct = 0; ct < 8; ++ct) {
        float bv = b2[ct * 16 + m];
#pragma unroll
        for (int r = 0; r < 4; ++r) {
            float v = fmaxf(acc2[ct][r] + bv, 0.f);
            tls[wv * 16 + q * 4 + r][ct * 16 + m] = f2bf(v);
        }
    }
    __syncthreads();
    const long base_row = (long)blockIdx.x * 64;
#pragma unroll
    for (int it = 0; it < 4; ++it) {
        int chunk = threadIdx.x + it * 256;   // 0..1023
        int row = chunk >> 4;
        int c8 = (chunk & 15) * 8;
        *(uint4*)(outb + (base_row + row) * 128 + c8) = *(const uint4*)(&tls[row][c8]);
    }
}

// ---------------- global mean pool (two-stage, grid-parallel) ----------------

__global__ __launch_bounds__(128) void pool1_kernel(
    const u16* __restrict__ h2b, const int* __restrict__ batch,
    float* __restrict__ acc, int N, int rows_per_block)
{
    int c = threadIdx.x;
    int r0 = blockIdx.x * rows_per_block;
    if (r0 >= N) return;
    int r1 = r0 + rows_per_block;
    if (r1 > N) r1 = N;
    int cur = batch[r0];
    float sum = 0.f;
    for (int r = r0; r < r1; ++r) {
        int g = batch[r];
        float v = bf2f((u32)h2b[(long)r * 128 + c]);
        if (g != cur) {
            atomicAdd(&acc[cur * 128 + c], sum);
            sum = 0.f;
            cur = g;
        }
        sum += v;
    }
    atomicAdd(&acc[cur * 128 + c], sum);
}

__global__ __launch_bounds__(128) void pool2_kernel(
    const float* __restrict__ acc, const int* __restrict__ batch,
    float* __restrict__ out, int n)
{
    int g = blockIdx.x;
    int c = threadIdx.x;
    int lo = 0, hi = n;
    while (lo < hi) { int mid = (lo + hi) >> 1; if (batch[mid] < g) lo = mid + 1; else hi = mid; }
    int s = lo;
    lo = s; hi = n;
    while (lo < hi) { int mid = (lo + hi) >> 1; if (batch[mid] < g + 1) lo = mid + 1; else hi = mid; }
    int cnt = lo - s;
    out[g * 128 + c] = acc[g * 128 + c] / (float)(cnt > 0 ? cnt : 1);
}

// ---------------- launch ----------------
extern "C" void kernel_launch(void* const* d_in, const int* in_sizes, int n_in,
                              void* d_out, int out_size, void* d_ws, size_t ws_size,
                              hipStream_t stream)
{
    const float* x      = (const float*)d_in[0];
    const int*   ei     = (const int*)d_in[1];
    const float* eattr  = (const float*)d_in[2];
    const int*   batch  = (const int*)d_in[3];
    const float* ne_w   = (const float*)d_in[4];
    const float* ne_b   = (const float*)d_in[5];
    const float* ee_w   = (const float*)d_in[6];
    const float* ee_b   = (const float*)d_in[7];
    const float* lin1_w = (const float*)d_in[8];
    const float* lin1_b = (const float*)d_in[9];
    const float* w11    = (const float*)d_in[10];
    const float* b11    = (const float*)d_in[11];
    const float* w12    = (const float*)d_in[12];
    const float* b12    = (const float*)d_in[13];
    const float* lin2_w = (const float*)d_in[14];
    const float* lin2_b = (const float*)d_in[15];
    const float* w21    = (const float*)d_in[16];
    const float* b21    = (const float*)d_in[17];
    const float* w22    = (const float*)d_in[18];
    const float* b22    = (const float*)d_in[19];

    const int N = in_sizes[0];
    const int E = in_sizes[2];
    const int G = out_size / 128;
    const int Npad = ((N + 63) / 64) * 64;
    const int nb = (N + 511) >> 9;     // coarse buckets of 512 nodes
    const int* esrc = ei;
    const int* edst = ei + E;

    char* p = (char*)d_ws;
    auto alloc = [&](size_t bytes) -> void* {
        void* r = (void*)p;
        p += (bytes + 255) & ~(size_t)255;
        return r;
    };
    float* u1 = (float*)alloc(128 * 4);
    float* C1 = (float*)alloc(128 * 4);
    float* u2 = (float*)alloc(128 * 4);
    float* C2 = (float*)alloc(128 * 4);
    int* deg    = (int*)alloc((size_t)N * 4);
    int* incl   = (int*)alloc((size_t)N * 4);
    int* bsum   = (int*)alloc(4096);
    int* boff   = (int*)alloc(4096);
    int* rowptr = (int*)alloc(((size_t)N + 1) * 4);
    int* cursor = (int*)alloc((size_t)N * 4);
    int* bstart = (int*)alloc(((size_t)nb + 1) * 4);
    int* bcur   = (int*)alloc((size_t)nb * 4);
    int2* edges = (int2*)alloc((size_t)E * 8);
    int2* binned = (int2*)alloc((size_t)E * 8);
    u16* binned_dlo = (u16*)alloc((size_t)E * 2);
    u16* w11hi = (u16*)alloc(16384 * 2);
    u16* w11lo = (u16*)alloc(16384 * 2);
    u16* w12hi = (u16*)alloc(16384 * 2);
    u16* w12lo = (u16*)alloc(16384 * 2);
    u16* w21hi = (u16*)alloc(16384 * 2);
    u16* w21lo = (u16*)alloc(16384 * 2);
    u16* w22hi = (u16*)alloc(16384 * 2);
    u16* w22lo = (u16*)alloc(16384 * 2);
    u16* bufA = (u16*)alloc((size_t)Npad * 128 * 2);
    u16* bufB = (u16*)alloc((size_t)Npad * 128 * 2);
    float* poolacc = (float*)alloc((size_t)G * 128 * 4);

    const int nbScan = (N + 1023) / 1024;

    hipMemsetAsync(deg, 0, (size_t)N * 4, stream);
    hipMemsetAsync(poolacc, 0, (size_t)G * 128 * 4, stream);
    consts_kernel<<<1, 128, 0, stream>>>(ne_b, ee_w, ee_b, lin1_w, lin1_b, lin2_w, lin2_b,
                                         u1, C1, u2, C2);
    prepack_kernel<<<64, 256, 0, stream>>>(w11, w11hi, w11lo);
    prepack_kernel<<<64, 256, 0, stream>>>(w12, w12hi, w12lo);
    prepack_kernel<<<64, 256, 0, stream>>>(w21, w21hi, w21lo);
    prepack_kernel<<<64, 256, 0, stream>>>(w22, w22hi, w22lo);

    count_kernel<<<(E + 1023) / 1024, 256, 0, stream>>>(edst, deg, E);
    scan1_kernel<<<nbScan, 1024, 0, stream>>>(deg, incl, bsum, N);
    scan2_kernel<<<1, 1024, 0, stream>>>(bsum, boff, nbScan);
    scan3_kernel<<<nbScan, 1024, 0, stream>>>(deg, incl, boff, rowptr, cursor, N);

    bucket_init_kernel<<<(nb + 256) / 256, 256, 0, stream>>>(rowptr, bstart, bcur, N, nb);
    bin_kernel<<<(E + 4095) / 4096, 1024, 0, stream>>>(esrc, edst, eattr, bcur,
                                                       binned, binned_dlo, E, nb);
    fine_kernel<<<nb, 1024, 0, stream>>>(binned, binned_dlo, bstart, cursor, edges);

    pull1_kernel<<<(N + 3) / 4, 256, 0, stream>>>(x, rowptr, edges, ne_w, ne_b, u1, C1,
                                                  bufA, N);
    mlp_kernel<<<Npad / 64, 256, 0, stream>>>(bufA, w11hi, w11lo, w12hi, w12lo, b11, b12, bufB);
    pull2_kernel<<<(N + 3) / 4, 256, 0, stream>>>(bufB, rowptr, edges, u2, C2, bufA, N);
    mlp_kernel<<<Npad / 64, 256, 0, stream>>>(bufA, w21hi, w21lo, w22hi, w22lo, b21, b22, bufB);

    const int rows_per_block = 128;
    pool1_kernel<<<(N + rows_per_block - 1) / rows_per_block, 128, 0, stream>>>(
        bufB, batch, poolacc, N, rows_per_block);
    pool2_kernel<<<G, 128, 0, stream>>>(poolacc, batch, (float*)d_out, N);
}